// Round 10
// baseline (154.806 us; speedup 1.0000x reference)
//
#include <hip/hip_runtime.h>

#define TS 64
#define NB 256
#define DI 32
#define NH 10
#define IND 42

typedef float f32x2 __attribute__((ext_vector_type(2)));

// ---- packed-f32 VOP3P helpers. op_sel[i]: which half of src i feeds the
// LO op; op_sel_hi[i]: which half feeds the HI op; neg_* negate that src.
#define PKOP2(name, instr, mods) \
__device__ __forceinline__ f32x2 name(f32x2 a, f32x2 b){ \
  f32x2 d; asm(instr " %0, %1, %2 " mods : "=v"(d) : "v"(a), "v"(b)); return d; }
#define PKOP3(name, mods) \
__device__ __forceinline__ f32x2 name(f32x2 a, f32x2 b, f32x2 c){ \
  f32x2 d; asm("v_pk_fma_f32 %0, %1, %2, %3 " mods : "=v"(d) : "v"(a), "v"(b), "v"(c)); return d; }

PKOP2(pk_add_p,   "v_pk_add_f32", "op_sel:[0,0] op_sel_hi:[1,1]")                    // {a.l+b.l, a.h+b.h}
PKOP2(pk_sub_p,   "v_pk_add_f32", "op_sel:[0,0] op_sel_hi:[1,1] neg_lo:[0,1] neg_hi:[0,1]") // {a.l-b.l, a.h-b.h}
PKOP2(pk_mul_bl,  "v_pk_mul_f32", "op_sel:[0,0] op_sel_hi:[1,0]")                    // {a.l*b.l, a.h*b.l}
PKOP2(pk_mul_bh,  "v_pk_mul_f32", "op_sel:[0,1] op_sel_hi:[1,1]")                    // {a.l*b.h, a.h*b.h}
PKOP2(pk_mul_bl_na,"v_pk_mul_f32","op_sel:[0,0] op_sel_hi:[1,0] neg_lo:[1,0] neg_hi:[1,0]") // {-a.l*b.l, -a.h*b.l}
PKOP3(pk_fma_bl,  "op_sel:[0,0,0] op_sel_hi:[1,0,1]")                                // a*b.l + c
PKOP3(pk_fma_bh,  "op_sel:[0,1,0] op_sel_hi:[1,1,1]")                                // a*b.h + c
PKOP3(pk_fma_bh_na,"op_sel:[0,1,0] op_sel_hi:[1,1,1] neg_lo:[1,0,0] neg_hi:[1,0,0]") // -a*b.h + c
PKOP3(pk_fma_bl_nac,"op_sel:[0,0,0] op_sel_hi:[1,0,1] neg_lo:[1,0,1] neg_hi:[1,0,1]")// -a*b.l - c

// uniform broadcast from a fixed lane
__device__ __forceinline__ float rl(float v, int lane){
  return __int_as_float(__builtin_amdgcn_readlane(__float_as_int(v), lane));
}
__device__ __forceinline__ void pin(float& x){ asm volatile("" : "+v"(x)); }
__device__ __forceinline__ void pinv(f32x2& x){ asm volatile("" : "+v"(x)); }

__device__ __forceinline__ float tanhr(float x){ float e = __expf(2.f*x); return 1.f - 2.f/(e + 1.f); }

// combined U = RY(t3)*RX(t2)*RZ(t1) -> 8 floats (row0 r/i pairs, row1 r/i pairs)
__device__ __forceinline__ void mkU(float t1, float t2, float t3, float* dst){
  float c1 = __cosf(0.5f*t1), s1 = __sinf(0.5f*t1);
  float c2 = __cosf(0.5f*t2), s2 = __sinf(0.5f*t2);
  float c3 = __cosf(0.5f*t3), s3 = __sinf(0.5f*t3);
  float A00r =  c2*c1, A00i = -c2*s1;
  float A01r =  s2*s1, A01i = -s2*c1;
  float A10r = -s2*s1, A10i = -s2*c1;
  float A11r =  c2*c1, A11i =  c2*s1;
  dst[0] = c3*A00r - s3*A10r; dst[1] = c3*A00i - s3*A10i;
  dst[2] = c3*A01r - s3*A11r; dst[3] = c3*A01i - s3*A11i;
  dst[4] = s3*A00r + c3*A10r; dst[5] = s3*A00i + c3*A10i;
  dst[6] = s3*A01r + c3*A11r; dst[7] = s3*A01i + c3*A11i;
}

__device__ __forceinline__ float3 qf(float q00, float q11, float q01){
  return make_float3(0.5f*(q00+q11), 0.5f*(q00-q11), 0.5f*q01);
}

// R18-verified per-wire map, sg-major packed (bit-identical rounding).
// State pairs Q,S,A,B hold {sg_i, sg_j}; W1={n0,n1}, W2={e1r,e1i} scalar per
// (gate,wire); K1={Cp,Cm}, K3={Cr2,Ci2}, K5={Ci4,Cr4} scalar per wire.
__device__ __forceinline__ void wire_step(f32x2& Q, f32x2& S, f32x2& A, f32x2& B,
                                          f32x2 W1, f32x2 W2,
                                          f32x2 K1w, f32x2 K3w, f32x2 K5w){
  f32x2 u0 = pk_add_p(Q, A);
  f32x2 u3 = pk_sub_p(Q, A);
  f32x2 m0 = pk_mul_bl(u0, W1);            // *n0
  f32x2 m3 = pk_mul_bh(u3, W1);            // *n1
  f32x2 t1 = pk_mul_bl(S, W2);             // S*e1r
  f32x2 am = pk_fma_bh_na(B, W2, t1);      // -Bn*e1i + t1
  f32x2 t2 = pk_mul_bh(S, W2);             // S*e1i
  f32x2 bm = pk_fma_bl(B, W2, t2);         // Bn*e1r + t2
  f32x2 q2 = pk_add_p(m0, m3);
  f32x2 s2 = pk_sub_p(m0, m3);
  f32x2 am2 = pk_add_p(am, am);
  f32x2 t3 = pk_mul_bl(q2, K1w);           // q2*Cp
  Q = pk_fma_bh(am2, K1w, t3);             // +am2*Cm
  f32x2 t4 = pk_mul_bh(q2, K1w);           // q2*Cm
  S = pk_fma_bl(am2, K1w, t4);             // +am2*Cp
  f32x2 t5 = pk_mul_bl_na(bm, K5w);        // -(bm*Ci4)
  A = pk_fma_bl(s2, K3w, t5);              // s2*Cr2 + t5
  f32x2 t6 = pk_mul_bh(bm, K5w);           // bm*Cr4
  B = pk_fma_bh(s2, K3w, t6);              // s2*Ci2 + t6
}

// R21: ONE WAVE per batch element -- zero barriers. Key fact: chain
// constants (lBw, K's, k-inits) are gate-independent (qparams shared);
// only W.x, w_h, activation differ per gate. lane = g*16+hq (4 gates x
// 10 wires; hq>=10 lanes compute safe garbage). Each lane runs all 4
// sg-chains, sg-major packed into 2 pair-sets -> R18 map, bit-identical.
// Gate exchange + v-sharing are same-wave LDS (in-order DS pipe, lgkm
// only -- no __syncthreads anywhere). R20 model: 4-wave step = ~1960cyc
// with ~1350 stall (barrier+skew+exchange); this removes the barrier
// class entirely at the cost of 4x per-lane chain issue on 1 SIMD.
__global__ __launch_bounds__(64) __attribute__((amdgpu_waves_per_eu(1, 1)))
void qlstm_kernel(const float* __restrict__ xin,
                  const float* __restrict__ qp,
                  const float* __restrict__ Wf, const float* __restrict__ bfp,
                  const float* __restrict__ Wi, const float* __restrict__ bip,
                  const float* __restrict__ Wg, const float* __restrict__ bgp,
                  const float* __restrict__ Wo, const float* __restrict__ bop,
                  float* __restrict__ out)
{
  __shared__ float lx[TS][DI + 1];                 // staged x, +1 pad
  __shared__ float lwx[4][TS][NH];                 // W.x + bias, all 4 gates
  __shared__ __align__(16) float lBw[NH][4];       // B_w (gate-independent!)
  __shared__ __align__(16) float4 lvv[4][17];      // per-step {n0,n1,e1r,e1i}
  __shared__ __align__(16) float lact[16][4];      // activated gates per wire
  __shared__ float lhout[TS][NH];                  // buffered h-outputs

  const int tid  = threadIdx.x;    // single wave: tid == lane
  const int b    = blockIdx.x;
  const int g    = tid >> 4;       // gate 0..3
  const int hq   = tid & 15;       // wire (valid < 10)
  const int hrow = (hq < NH) ? hq : 0;

  const float* Wsel = (g==0) ? Wf : (g==1) ? Wi : (g==2) ? Wg : Wo;

  // ---- stage x coalesced (64-lane loop) ----
  for (int i = tid; i < TS*DI; i += 64) {
    int tt = i >> 5, d = i & 31;
    lx[tt][d] = xin[(size_t)tt*(NB*DI) + b*DI + d];
  }
  // ---- layer-2 B matrices (single copy; lanes 0..9) ----
  if (tid < NH) {
    float u[8];
    mkU(qp[30 + tid*3 + 0], qp[30 + tid*3 + 1], qp[30 + tid*3 + 2], u);
    float B00 = u[0]*u[0]+u[1]*u[1] - (u[4]*u[4]+u[5]*u[5]);
    float B11 = u[2]*u[2]+u[3]*u[3] - (u[6]*u[6]+u[7]*u[7]);
    float B01r= u[0]*u[2]+u[1]*u[3] - (u[4]*u[6]+u[5]*u[7]);
    float B01i= u[1]*u[2]-u[0]*u[3] - (u[5]*u[6]-u[4]*u[7]);
    *reinterpret_cast<float4*>(&lBw[tid][0]) = make_float4(B00,B11,B01r,B01i);
  }
  // (single wave: program-order DS visibility, no barrier needed)

  // ---- precompute W.x + bias for all 4 gates, lane == t ----
  #pragma unroll
  for (int gg = 0; gg < 4; gg++) {
    const float* W  = (gg==0) ? Wf : (gg==1) ? Wi : (gg==2) ? Wg : Wo;
    const float* bv = (gg==0) ? bfp : (gg==1) ? bip : (gg==2) ? bgp : bop;
    float acc[NH];
    #pragma unroll
    for (int h = 0; h < NH; h++) acc[h] = bv[h];
    #pragma unroll
    for (int k = 0; k < DI; k++) {
      float xk = lx[tid][k];
      #pragma unroll
      for (int h = 0; h < NH; h++) acc[h] = fmaf(W[h*IND + k], xk, acc[h]);
    }
    #pragma unroll
    for (int h = 0; h < NH; h++) lwx[gg][tid][h] = acc[h];
  }

  // ---- recurrent weights (lane's gate, lane's wire-row) ----
  float wh[NH];
  #pragma unroll
  for (int j = 0; j < NH; j++) wh[j] = Wsel[hrow*IND + DI + j];

  // ---- conv-data quadratic forms for wire hrow (gate-independent) ----
  float3 Qn0, Qn1, Qer, Qei;
  {
    float U1[8];
    mkU(qp[hrow*3+0], qp[hrow*3+1], qp[hrow*3+2], U1);
    float r00r=U1[0], r00i=U1[1], r01r=U1[2], r01i=U1[3];
    float r10r=U1[4], r10i=U1[5], r11r=U1[6], r11i=U1[7];
    float P0r,P0i,P1r,P1i, R0r,R0i,R1r,R1i;
    if (hq == 0) {                 // wire 0 uses rows directly
      P0r=r00r; P0i=r00i; P1r=r01r; P1i=r01i;
      R0r=r10r; R0i=r10i; R1r=r11r; R1i=r11i;
    } else {
      P0r=0.5f*(r00r+r10r); P0i=0.5f*(r00i+r10i);
      P1r=0.5f*(r01r+r11r); P1i=0.5f*(r01i+r11i);
      R0r=0.5f*(r00r-r10r); R0i=0.5f*(r00i-r10i);
      R1r=0.5f*(r01r-r11r); R1i=0.5f*(r01i-r11i);
    }
    Qn0 = qf(P0r*P0r+P0i*P0i, P1r*P1r+P1i*P1i, 2.f*(P0r*P1r+P0i*P1i));
    Qn1 = qf(R0r*R0r+R0i*R0i, R1r*R1r+R1i*R1i, 2.f*(R0r*R1r+R0i*R1i));
    Qer = qf(R0r*P0r+R0i*P0i, R1r*P1r+R1i*P1i,
             (R0r*P1r+R0i*P1i) + (R1r*P0r+R1i*P0i));
    Qei = qf(R0i*P0r-R0r*P0i, R1i*P1r-R1r*P1i,
             (R0i*P1r-R0r*P1i) + (R1i*P0r-R1r*P0i));
  }
  f32x2 QnA, QnB, QnG, QeA, QeB, QeG;
  QnA.x=Qn0.x; QnA.y=Qn1.x;  QnB.x=Qn0.y; QnB.y=Qn1.y;  QnG.x=Qn0.z; QnG.y=Qn1.z;
  QeA.x=Qer.x; QeA.y=Qei.x;  QeB.x=Qer.y; QeB.y=Qei.y;  QeG.x=Qer.z; QeG.y=Qei.z;

  // ---- chain init constants: all 4 sg per lane, packed {sg0,sg1},{sg2,sg3}
  //      gsc = (0.5,1,1,0.5) pick-scale folded in (R18 linearity) ----
  float4 b0 = *reinterpret_cast<const float4*>(&lBw[0][0]);
  if (hq == 0) b0 = make_float4(1.f, 1.f, 0.f, 0.f);   // E0 mask excludes wire 0
  f32x2 k0a, k0b, k3a, k3b, ka2a, ka2b, kb2a, kb2b;
  {
    float k0_0 = 0.5f*b0.x, k3_0 = 0.5f*b0.y, ka_0 = 0.5f*b0.z, kb_0 = -0.5f*b0.w;
    float k0_1 = b0.z,      k3_1 = b0.z,      ka_1 = 0.5f*(b0.x+b0.y), kb_1 = 0.f;
    float k0_2 = -b0.w,     k3_2 = b0.w,      ka_2 = 0.f, kb_2 = 0.5f*(b0.y-b0.x);
    float k0_3 = 0.5f*b0.y, k3_3 = 0.5f*b0.x, ka_3 = 0.5f*b0.z, kb_3 = 0.5f*b0.w;
    k0a.x=k0_0; k0a.y=k0_1;   k0b.x=k0_2; k0b.y=k0_3;
    k3a.x=k3_0; k3a.y=k3_1;   k3b.x=k3_2; k3b.y=k3_3;
    ka2a.x=ka_0+ka_0; ka2a.y=ka_1+ka_1;  ka2b.x=ka_2+ka_2; ka2b.y=ka_3+ka_3;
    kb2a.x=kb_0+kb_0; kb2a.y=kb_1+kb_1;  kb2b.x=kb_2+kb_2; kb2b.y=kb_3+kb_3;
  }

  // ---- per-wire packed constants (gate-independent, mask by hq) ----
  f32x2 K1c[9], K3c[9], K5c[9];
  #pragma unroll
  for (int w = 1; w <= 9; w++) {
    float4 bb = *reinterpret_cast<const float4*>(&lBw[w][0]);
    bool inM = (hq == 0) || (w <= hq);        // M_0={1..9}, M_h={0..h}
    float Cp  = inM ? (bb.x + bb.y) : 2.f;
    float Cm  = inM ? (bb.x - bb.y) : 0.f;
    float Cr2 = inM ? (bb.z + bb.z) : 0.f;
    float Ci2 = inM ? (bb.w + bb.w) : 0.f;
    K1c[w-1].x = Cp;        K1c[w-1].y = Cm;
    K3c[w-1].x = Cr2;       K3c[w-1].y = Ci2;
    K5c[w-1].x = Ci2 + Ci2; K5c[w-1].y = Cr2 + Cr2;   // {Ci4, Cr4}
  }

  // ---- pin constants into VGPRs (512-reg budget at 1 wave/EU) ----
  #pragma unroll
  for (int w = 0; w < 9; w++) { pinv(K1c[w]); pinv(K3c[w]); pinv(K5c[w]); }
  #pragma unroll
  for (int j = 0; j < NH; j++) pin(wh[j]);
  pinv(QnA); pinv(QnB); pinv(QnG); pinv(QeA); pinv(QeB); pinv(QeG);
  pinv(k0a); pinv(k0b); pinv(k3a); pinv(k3b);
  pinv(ka2a); pinv(ka2b); pinv(kb2a); pinv(kb2b);

  // wave-... lane-uniform-per-gate activation: g==2 -> tanh = 2*sigm(2x)-1
  const float se = (g == 2) ? -2.f : -1.f;
  const float sa = (g == 2) ?  2.f :  1.f;
  const float sb = (g == 2) ? -1.f :  0.f;

  float cstate = 0.f, hval = 0.f;
  float wxcur = lwx[g][0][hrow];      // prefetched W.x for t=0

  for (int t = 0; t < TS; t++) {
    // ---- (a) pre-activation: prefetched wx + tree-reduced recurrent dot ----
    float h0 = rl(hval,0), h1 = rl(hval,1), h2 = rl(hval,2), h3 = rl(hval,3), h4 = rl(hval,4);
    float h5 = rl(hval,5), h6 = rl(hval,6), h7 = rl(hval,7), h8 = rl(hval,8), h9 = rl(hval,9);
    float p0 = fmaf(wh[1], h1, wh[0]*h0);
    float p1 = fmaf(wh[3], h3, wh[2]*h2);
    float p2 = fmaf(wh[5], h5, wh[4]*h4);
    float p3 = fmaf(wh[7], h7, wh[6]*h6);
    float p4 = fmaf(wh[9], h9, wh[8]*h8);
    float pre = wxcur + ((p0 + p1) + (p2 + p3) + p4);

    wxcur = lwx[g][(t+1) & (TS-1)][hrow];   // prefetch next step

    // ---- (b) v's for (gate g, wire hq); share via same-wave LDS ----
    float th = pre * 0.15915494309189535f;
    f32x2 CS; CS.x = __builtin_amdgcn_cosf(th); CS.y = __builtin_amdgcn_sinf(th);
    f32x2 NP = pk_fma_bl(QnB, CS, pk_fma_bh(QnG, CS, QnA));   // {n0v, n1v}
    f32x2 EP = pk_fma_bl(QeB, CS, pk_fma_bh(QeG, CS, QeA));   // {e1rv, e1iv}
    float4 vs; vs.x = NP.x; vs.y = NP.y; vs.z = EP.x; vs.w = EP.y;
    lvv[g][hq] = vs;
    // (in-order DS pipe: subsequent reads see all lanes' writes)

    // ---- (c) packed 4-chain: sets a={sg0,sg1}, b={sg2,sg3} ----
    float4 v0 = lvv[g][0];
    f32x2 W1, W2;
    W1.x = v0.x; W1.y = v0.y; W2.x = v0.z; W2.y = v0.w;
    f32x2 ta = pk_mul_bl(k0a, W1);            // k0*vx0
    f32x2 Qa = pk_fma_bh(k3a, W1, ta);        // +k3*vy0
    f32x2 Sa = pk_fma_bh_na(k3a, W1, ta);     // -k3*vy0 + ta
    f32x2 ua = pk_mul_bl(ka2a, W2);           // ka2*vr0
    f32x2 Aa = pk_fma_bh_na(kb2a, W2, ua);    // -kb2*vi0 + ua
    f32x2 va = pk_mul_bh(ka2a, W2);           // ka2*vi0
    f32x2 Ba = pk_fma_bl_nac(kb2a, W2, va);   // -kb2*vr0 - va
    f32x2 tb = pk_mul_bl(k0b, W1);
    f32x2 Qb = pk_fma_bh(k3b, W1, tb);
    f32x2 Sb = pk_fma_bh_na(k3b, W1, tb);
    f32x2 ub = pk_mul_bl(ka2b, W2);
    f32x2 Ab = pk_fma_bh_na(kb2b, W2, ub);
    f32x2 vb = pk_mul_bh(ka2b, W2);
    f32x2 Bb = pk_fma_bl_nac(kb2b, W2, vb);
    #pragma unroll
    for (int w = 1; w <= 9; w++) {
      float4 vv = lvv[g][w];
      W1.x = vv.x; W1.y = vv.y; W2.x = vv.z; W2.y = vv.w;
      wire_step(Qa, Sa, Aa, Ba, W1, W2, K1c[w-1], K3c[w-1], K5c[w-1]);
      wire_step(Qb, Sb, Ab, Bb, W1, W2, K1c[w-1], K3c[w-1], K5c[w-1]);
    }

    // ---- (d) in-lane pick+sum (was dpp quad-sum): E0+E1+E2+E3 ----
    float Ee = ((Qa.x + Sa.x) + Aa.y) + (Bb.x + (Qb.y - Sb.y));

    // ---- (e) activation, then same-wave gate exchange (no barrier) ----
    float act = fmaf(sa, 1.f/(1.f + __expf(se*Ee)), sb);
    lact[hq][g] = act;
    float4 gates = *reinterpret_cast<const float4*>(&lact[hq][0]);   // {f,i,g,o}

    // ---- (f) LSTM cell (redundant across gate groups, identical) ----
    cstate = gates.x*cstate + gates.y*gates.z;
    hval = gates.w*tanhr(cstate);
    if (tid < NH) lhout[t][tid] = hval;    // lanes 0..9 = wires 0..9
  }

  // ---- bulk coalesced h-output write (off the serial path) ----
  for (int i = tid; i < TS*NH; i += 64) {
    int tt = i / NH, h = i - tt*NH;
    out[(size_t)tt*(NB*NH) + b*NH + h] = lhout[tt][h];
  }
  if (tid < NH) {
    out[(size_t)TS*NB*NH + b*NH + tid]          = hval;
    out[(size_t)TS*NB*NH + NB*NH + b*NH + tid]  = cstate;
  }
}

extern "C" void kernel_launch(void* const* d_in, const int* in_sizes, int n_in,
                              void* d_out, int out_size, void* d_ws, size_t ws_size,
                              hipStream_t stream) {
  (void)in_sizes; (void)n_in; (void)d_ws; (void)ws_size; (void)out_size;
  qlstm_kernel<<<dim3(NB), dim3(64), 0, stream>>>(
      (const float*)d_in[0], (const float*)d_in[1],
      (const float*)d_in[2], (const float*)d_in[3],
      (const float*)d_in[4], (const float*)d_in[5],
      (const float*)d_in[6], (const float*)d_in[7],
      (const float*)d_in[8], (const float*)d_in[9],
      (float*)d_out);
}

// Round 12
// 149.356 us; speedup vs baseline: 1.0365x; 1.0365x over previous
//
#include <hip/hip_runtime.h>

#define TS 64
#define NB 256
#define DI 32
#define NH 10
#define IND 42

typedef float f32x2 __attribute__((ext_vector_type(2)));

// ---- packed-f32 VOP3P helpers. Pair dim = 2 BATCH ELEMENTS {A,B}.
// op_sel[i] selects src-i half for the LO op; op_sel_hi[i] for the HI op;
// neg_lo/neg_hi negate that source in lo/hi. Per-half rounding = IEEE fma.
// R23: volatile (no CSE/motion) -- miscompile-surface elimination.
#define PKOP2(name, instr, mods) \
__device__ __forceinline__ f32x2 name(f32x2 a, f32x2 b){ \
  f32x2 d; asm volatile(instr " %0, %1, %2 " mods : "=v"(d) : "v"(a), "v"(b)); return d; }
#define PKOP3(name, mods) \
__device__ __forceinline__ f32x2 name(f32x2 a, f32x2 b, f32x2 c){ \
  f32x2 d; asm volatile("v_pk_fma_f32 %0, %1, %2, %3 " mods : "=v"(d) : "v"(a), "v"(b), "v"(c)); return d; }

PKOP2(pk_add_p,    "v_pk_add_f32", "op_sel:[0,0] op_sel_hi:[1,1]")                    // {a.l+b.l, a.h+b.h}
PKOP2(pk_sub_p,    "v_pk_add_f32", "op_sel:[0,0] op_sel_hi:[1,1] neg_lo:[0,1] neg_hi:[0,1]") // a-b
PKOP2(pk_mul_pp,   "v_pk_mul_f32", "op_sel:[0,0] op_sel_hi:[1,1]")                    // {a.l*b.l, a.h*b.h}
PKOP2(pk_mul_bl,   "v_pk_mul_f32", "op_sel:[0,0] op_sel_hi:[1,0]")                    // {a.l*b.l, a.h*b.l}
PKOP2(pk_mul_bh,   "v_pk_mul_f32", "op_sel:[0,1] op_sel_hi:[1,1]")                    // {a.l*b.h, a.h*b.h}
PKOP2(pk_mul_bh_na,"v_pk_mul_f32", "op_sel:[0,1] op_sel_hi:[1,1] neg_lo:[1,0] neg_hi:[1,0]") // -a*b.h
PKOP3(pk_fma_pp,   "op_sel:[0,0,0] op_sel_hi:[1,1,1]")                                // a*b + c
PKOP3(pk_fma_na,   "op_sel:[0,0,0] op_sel_hi:[1,1,1] neg_lo:[1,0,0] neg_hi:[1,0,0]")  // -a*b + c
PKOP3(pk_fma_bl,   "op_sel:[0,0,0] op_sel_hi:[1,0,1]")                                // a*b.l + c
PKOP3(pk_fma_bh,   "op_sel:[0,1,0] op_sel_hi:[1,1,1]")                                // a*b.h + c
PKOP3(pk_fma_bh_na,"op_sel:[0,1,0] op_sel_hi:[1,1,1] neg_lo:[1,0,0] neg_hi:[1,0,0]")  // -a*b.h + c
PKOP3(pk_fma_bh_nac,"op_sel:[0,1,0] op_sel_hi:[1,1,1] neg_lo:[1,0,1] neg_hi:[1,0,1]") // -a*b.h - c

// DPP quad_perm xor-exchange: 0xB1 = xor1, 0x4E = xor2 (VALU pipe)
template<int CTRL>
__device__ __forceinline__ float dppx(float v){
  return __int_as_float(__builtin_amdgcn_update_dpp(
      0, __float_as_int(v), CTRL, 0xF, 0xF, true));
}
__device__ __forceinline__ float rl(float v, int lane){
  return __int_as_float(__builtin_amdgcn_readlane(__float_as_int(v), lane));
}
__device__ __forceinline__ f32x2 rl2(f32x2 v, int lane){
  f32x2 r; r.x = rl(v.x, lane); r.y = rl(v.y, lane); return r;
}

__device__ __forceinline__ float tanhr(float x){ float e = __expf(2.f*x); return 1.f - 2.f/(e + 1.f); }

// combined U = RY(t3)*RX(t2)*RZ(t1) -> 8 floats (row0 r/i pairs, row1 r/i pairs)
__device__ __forceinline__ void mkU(float t1, float t2, float t3, float* dst){
  float c1 = __cosf(0.5f*t1), s1 = __sinf(0.5f*t1);
  float c2 = __cosf(0.5f*t2), s2 = __sinf(0.5f*t2);
  float c3 = __cosf(0.5f*t3), s3 = __sinf(0.5f*t3);
  float A00r =  c2*c1, A00i = -c2*s1;
  float A01r =  s2*s1, A01i = -s2*c1;
  float A10r = -s2*s1, A10i = -s2*c1;
  float A11r =  c2*c1, A11i =  c2*s1;
  dst[0] = c3*A00r - s3*A10r; dst[1] = c3*A00i - s3*A10i;
  dst[2] = c3*A01r - s3*A11r; dst[3] = c3*A01i - s3*A11i;
  dst[4] = s3*A00r + c3*A10r; dst[5] = s3*A00i + c3*A10i;
  dst[6] = s3*A01r + c3*A11r; dst[7] = s3*A01i + c3*A11i;
}

__device__ __forceinline__ float3 qf(float q00, float q11, float q01){
  return make_float3(0.5f*(q00+q11), 0.5f*(q00-q11), 0.5f*q01);
}

// R18-verified per-wire map on ELEMENT-pairs; wire consts scalar broadcast:
// Kp={Cp,Cm}, Kq={Cr2,Ci4}, Kr={Ci2,Cr4}. Per-elem rounding == R18 scalar.
__device__ __forceinline__ void wire_step2(f32x2& Q, f32x2& S, f32x2& A, f32x2& B,
    f32x2 vx, f32x2 vy, f32x2 vr, f32x2 vi, f32x2 Kp, f32x2 Kq, f32x2 Kr){
  f32x2 u0 = pk_add_p(Q, A);
  f32x2 u3 = pk_sub_p(Q, A);
  f32x2 m0 = pk_mul_pp(u0, vx);
  f32x2 m3 = pk_mul_pp(u3, vy);
  f32x2 t1 = pk_mul_pp(S, vr);
  f32x2 am = pk_fma_na(B, vi, t1);        // -Bn*vi + S*vr
  f32x2 t2 = pk_mul_pp(S, vi);
  f32x2 bm = pk_fma_pp(B, vr, t2);        //  Bn*vr + S*vi
  f32x2 q2 = pk_add_p(m0, m3);
  f32x2 s2 = pk_sub_p(m0, m3);
  f32x2 am2 = pk_add_p(am, am);
  f32x2 t3 = pk_mul_bl(q2, Kp);           // q2*Cp
  Q = pk_fma_bh(am2, Kp, t3);             // + am2*Cm
  f32x2 t4 = pk_mul_bh(q2, Kp);           // q2*Cm
  S = pk_fma_bl(am2, Kp, t4);             // + am2*Cp
  f32x2 t5 = pk_mul_bh_na(bm, Kq);        // -(bm*Ci4)
  A = pk_fma_bl(s2, Kq, t5);              // s2*Cr2 + t5
  f32x2 t6 = pk_mul_bh(bm, Kr);           // bm*Cr4
  B = pk_fma_bl(s2, Kr, t6);              // s2*Ci2 + t6
}

// R23: R22 (2 batch elems via f32x2 pair dim, R20 4-wave structure) with
// the three miscompile-suspect constructs removed: (1) all asm "+v" pins
// dropped (512-reg budget at waves_per_eu(1,1) makes them unnecessary);
// (2) pk asm volatile; (3) vector ternaries -> scalar component selects.
// Full instruction-level re-derivation vs R18 found zero logic errors in
// R22; if this still fails, next round reverts permanently to R20.
__global__ __launch_bounds__(256) __attribute__((amdgpu_waves_per_eu(1, 1)))
void qlstm_kernel(const float* __restrict__ xin,
                  const float* __restrict__ qp,
                  const float* __restrict__ Wf, const float* __restrict__ bfp,
                  const float* __restrict__ Wi, const float* __restrict__ bip,
                  const float* __restrict__ Wg, const float* __restrict__ bgp,
                  const float* __restrict__ Wo, const float* __restrict__ bop,
                  float* __restrict__ out)
{
  __shared__ float lx[2][TS][DI + 1];              // staged x, both elems
  __shared__ __align__(8) f32x2 lwx[4][TS][NH];    // W.x + bias pairs
  __shared__ __align__(16) float lBw[4][NH][4];    // B_w = U2^dag Z U2
  __shared__ __align__(16) f32x2 lq[2][NH][5];     // [buf][h][gate(+pad)]
  __shared__ __align__(8) f32x2 lhout[TS][NH];     // buffered h-output pairs

  const int tid  = threadIdx.x;
  const int bA   = blockIdx.x * 2;   // elems bA (pair.x), bA+1 (pair.y)
  const int g    = tid >> 6;
  const int lane = tid & 63;
  const int hq   = lane >> 2;        // mask index (valid < 10)
  const int sg   = lane & 3;         // 0:sigma0 1:H1 2:H2 3:sigma3
  const int hrow = (lane < NH) ? lane : 0;

  const float* Wsel = (g==0) ? Wf : (g==1) ? Wi : (g==2) ? Wg : Wo;
  const float* bsel = (g==0) ? bfp : (g==1) ? bip : (g==2) ? bgp : bop;

  // ---- stage x coalesced (both elems; TS*DI = 2048) ----
  for (int i = tid; i < 2*TS*DI; i += 256) {
    int ss = i >> 11, r = i & 2047, tt = r >> 5, d = r & 31;
    lx[ss][tt][d] = xin[(size_t)tt*(NB*DI) + (size_t)(bA + ss)*DI + d];
  }
  // ---- layer-2 B matrices (per-wave copy, elem-independent) ----
  if (lane < NH) {
    float u[8];
    mkU(qp[30 + lane*3 + 0], qp[30 + lane*3 + 1], qp[30 + lane*3 + 2], u);
    float B00 = u[0]*u[0]+u[1]*u[1] - (u[4]*u[4]+u[5]*u[5]);
    float B11 = u[2]*u[2]+u[3]*u[3] - (u[6]*u[6]+u[7]*u[7]);
    float B01r= u[0]*u[2]+u[1]*u[3] - (u[4]*u[6]+u[5]*u[7]);
    float B01i= u[1]*u[2]-u[0]*u[3] - (u[5]*u[6]-u[4]*u[7]);
    *reinterpret_cast<float4*>(&lBw[g][lane][0]) = make_float4(B00,B11,B01r,B01i);
  }
  __syncthreads();

  // ---- precompute W.x + bias for all t, both elems (lane == t) ----
  {
    float accA[NH], accB[NH];
    #pragma unroll
    for (int h = 0; h < NH; h++) { accA[h] = bsel[h]; accB[h] = bsel[h]; }
    #pragma unroll
    for (int k = 0; k < DI; k++) {
      float xkA = lx[0][lane][k], xkB = lx[1][lane][k];
      #pragma unroll
      for (int h = 0; h < NH; h++) {
        float w = Wsel[h*IND + k];
        accA[h] = fmaf(w, xkA, accA[h]);
        accB[h] = fmaf(w, xkB, accB[h]);
      }
    }
    #pragma unroll
    for (int h = 0; h < NH; h++) {
      f32x2 p; p.x = accA[h]; p.y = accB[h];
      lwx[g][lane][h] = p;
    }
  }

  // ---- recurrent weights as broadcast pairs ----
  f32x2 whp[NH];
  #pragma unroll
  for (int j = 0; j < NH; j++) {
    float w = Wsel[hrow*IND + DI + j];
    whp[j].x = w; whp[j].y = w;
  }

  // ---- conv-data quadratic forms for wire hrow (elem-independent) ----
  float3 Qn0, Qn1, Qer, Qei;
  {
    float U1[8];
    mkU(qp[hrow*3+0], qp[hrow*3+1], qp[hrow*3+2], U1);
    float r00r=U1[0], r00i=U1[1], r01r=U1[2], r01i=U1[3];
    float r10r=U1[4], r10i=U1[5], r11r=U1[6], r11i=U1[7];
    float P0r,P0i,P1r,P1i, R0r,R0i,R1r,R1i;
    if (lane == 0) {
      P0r=r00r; P0i=r00i; P1r=r01r; P1i=r01i;
      R0r=r10r; R0i=r10i; R1r=r11r; R1i=r11i;
    } else {
      P0r=0.5f*(r00r+r10r); P0i=0.5f*(r00i+r10i);
      P1r=0.5f*(r01r+r11r); P1i=0.5f*(r01i+r11i);
      R0r=0.5f*(r00r-r10r); R0i=0.5f*(r00i-r10i);
      R1r=0.5f*(r01r-r11r); R1i=0.5f*(r01i-r11i);
    }
    Qn0 = qf(P0r*P0r+P0i*P0i, P1r*P1r+P1i*P1i, 2.f*(P0r*P1r+P0i*P1i));
    Qn1 = qf(R0r*R0r+R0i*R0i, R1r*R1r+R1i*R1i, 2.f*(R0r*R1r+R0i*R1i));
    Qer = qf(R0r*P0r+R0i*P0i, R1r*P1r+R1i*P1i,
             (R0r*P1r+R0i*P1i) + (R1r*P0r+R1i*P0i));
    Qei = qf(R0i*P0r-R0r*P0i, R1i*P1r-R1r*P1i,
             (R0i*P1r-R0r*P1i) + (R1i*P0r-R1r*P0i));
  }
  // qeval pairs: value = alpha + beta*C + gamma*S; BG={beta,gamma}, Ax2={a,a}
  f32x2 BGn0, An0, BGn1, An1, BGer, Aer, BGei, Aei;
  BGn0.x=Qn0.y; BGn0.y=Qn0.z; An0.x=Qn0.x; An0.y=Qn0.x;
  BGn1.x=Qn1.y; BGn1.y=Qn1.z; An1.x=Qn1.x; An1.y=Qn1.x;
  BGer.x=Qer.y; BGer.y=Qer.z; Aer.x=Qer.x; Aer.y=Qer.x;
  BGei.x=Qei.y; BGei.y=Qei.z; Aei.x=Qei.x; Aei.y=Qei.x;

  // ---- chain init constants (sg-dep, elem-indep); gsc fold (R18) ----
  float4 b0 = *reinterpret_cast<const float4*>(&lBw[g][0][0]);
  if (hq == 0) b0 = make_float4(1.f, 1.f, 0.f, 0.f);   // E0 mask excludes wire 0
  float k0, k3, ka, kb;
  if      (sg == 0) { k0 = b0.x;  k3 = b0.y;  ka = b0.z; kb = -b0.w; }
  else if (sg == 1) { k0 = b0.z;  k3 = b0.z;  ka = 0.5f*(b0.x + b0.y); kb = 0.f; }
  else if (sg == 2) { k0 = -b0.w; k3 = b0.w;  ka = 0.f;  kb = 0.5f*(b0.y - b0.x); }
  else              { k0 = b0.y;  k3 = b0.x;  ka = b0.z; kb = b0.w; }
  {
    const float gsc = (sg == 0 || sg == 3) ? 0.5f : 1.0f;
    k0 *= gsc; k3 *= gsc; ka *= gsc; kb *= gsc;
  }
  f32x2 KK1, KK2;
  KK1.x = k0;      KK1.y = k3;        // {k0, k3}
  KK2.x = ka + ka; KK2.y = kb + kb;   // {ka2, kb2}

  // ---- per-wire const pairs Kp={Cp,Cm}, Kq={Cr2,Ci4}, Kr={Ci2,Cr4} ----
  f32x2 Kp[9], Kq[9], Kr[9];
  #pragma unroll
  for (int w = 1; w <= 9; w++) {
    float4 bb = *reinterpret_cast<const float4*>(&lBw[g][w][0]);
    bool inM = (hq == 0) || (w <= hq);        // M_0={1..9}, M_h={0..h}
    float Cpv = inM ? (bb.x + bb.y) : 2.f;
    float Cmv = inM ? (bb.x - bb.y) : 0.f;
    float Cr2 = inM ? (bb.z + bb.z) : 0.f;
    float Ci2 = inM ? (bb.w + bb.w) : 0.f;
    Kp[w-1].x = Cpv;       Kp[w-1].y = Cmv;
    Kq[w-1].x = Cr2;       Kq[w-1].y = Ci2 + Ci2;    // {Cr2, Ci4}
    Kr[w-1].x = Ci2;       Kr[w-1].y = Cr2 + Cr2;    // {Ci2, Cr4}
  }

  // wave-uniform activation constants: g==2 -> tanh(x) = 2*sigm(2x) - 1
  const float se = (g == 2) ? -2.f : -1.f;
  const float sa = (g == 2) ?  2.f :  1.f;
  const float sb = (g == 2) ? -1.f :  0.f;

  f32x2 cstate; cstate.x = 0.f; cstate.y = 0.f;
  f32x2 hval;   hval.x = 0.f;   hval.y = 0.f;
  f32x2 wxcur = lwx[g][0][hrow];      // prefetched W.x pair for t=0

  for (int t = 0; t < TS; t++) {
    const int tb = t & 1;

    // ---- (a) pre-activation pair: wx + recurrent dot (both elems) ----
    f32x2 h0p = rl2(hval,0), h1p = rl2(hval,1), h2p = rl2(hval,2), h3p = rl2(hval,3), h4p = rl2(hval,4);
    f32x2 h5p = rl2(hval,5), h6p = rl2(hval,6), h7p = rl2(hval,7), h8p = rl2(hval,8), h9p = rl2(hval,9);
    f32x2 p0 = pk_fma_bl(h1p, whp[1], pk_mul_bl(h0p, whp[0]));
    f32x2 p1 = pk_fma_bl(h3p, whp[3], pk_mul_bl(h2p, whp[2]));
    f32x2 p2 = pk_fma_bl(h5p, whp[5], pk_mul_bl(h4p, whp[4]));
    f32x2 p3 = pk_fma_bl(h7p, whp[7], pk_mul_bl(h6p, whp[6]));
    f32x2 p4 = pk_fma_bl(h9p, whp[9], pk_mul_bl(h8p, whp[8]));
    f32x2 pre = pk_add_p(wxcur,
                  pk_add_p(pk_add_p(pk_add_p(p0, p1), pk_add_p(p2, p3)), p4));

    wxcur = lwx[g][(t+1) & (TS-1)][hrow];   // prefetch next step

    // full-angle sin/cos per elem (|pre| small); 1/2pi scale
    float thA = pre.x * 0.15915494309189535f;
    float thB = pre.y * 0.15915494309189535f;
    f32x2 Cc, Ss;
    Cc.x = __builtin_amdgcn_cosf(thA); Cc.y = __builtin_amdgcn_cosf(thB);
    Ss.x = __builtin_amdgcn_sinf(thA); Ss.y = __builtin_amdgcn_sinf(thB);
    f32x2 n0p = pk_fma_bl(Cc, BGn0, pk_fma_bh(Ss, BGn0, An0));
    f32x2 n1p = pk_fma_bl(Cc, BGn1, pk_fma_bh(Ss, BGn1, An1));
    f32x2 erp = pk_fma_bl(Cc, BGer, pk_fma_bh(Ss, BGer, Aer));
    f32x2 eip = pk_fma_bl(Cc, BGei, pk_fma_bh(Ss, BGei, Aei));

    // ---- (c) chain on elem-pairs; v broadcasts via readlane ----
    f32x2 vx0 = rl2(n0p,0), vy0 = rl2(n1p,0), vr0 = rl2(erp,0), vi0 = rl2(eip,0);
    f32x2 t1i = pk_mul_bl(vx0, KK1);             // k0*vx0
    f32x2 Qc  = pk_fma_bh(vy0, KK1, t1i);        // +k3*vy0
    f32x2 Sc  = pk_fma_bh_na(vy0, KK1, t1i);     // -k3*vy0 + t
    f32x2 t2i = pk_mul_bl(vr0, KK2);             // ka2*vr0
    f32x2 Ac  = pk_fma_bh_na(vi0, KK2, t2i);     // -kb2*vi0 + t
    f32x2 t3i = pk_mul_bl(vi0, KK2);             // ka2*vi0
    f32x2 Bc  = pk_fma_bh_nac(vr0, KK2, t3i);    // -kb2*vr0 - t
    #pragma unroll
    for (int w = 1; w <= 9; w++) {
      f32x2 vxw = rl2(n0p, w), vyw = rl2(n1p, w);
      f32x2 vrw = rl2(erp, w), viw = rl2(eip, w);
      wire_step2(Qc, Sc, Ac, Bc, vxw, vyw, vrw, viw, Kp[w-1], Kq[w-1], Kr[w-1]);
    }

    // ---- (d) pick via scalar component selects + per-half dpp quad-sum ----
    float QpSx = Qc.x + Sc.x, QpSy = Qc.y + Sc.y;
    float QmSx = Qc.x - Sc.x, QmSy = Qc.y - Sc.y;
    float t0x = (sg & 1) ? Ac.x  : QpSx;
    float t0y = (sg & 1) ? Ac.y  : QpSy;
    float t1x = (sg & 1) ? QmSx : Bc.x;
    float t1y = (sg & 1) ? QmSy : Bc.y;
    float ex = (sg & 2) ? t1x : t0x;
    float ey = (sg & 2) ? t1y : t0y;
    ex += dppx<0xB1>(ex); ex += dppx<0x4E>(ex);
    ey += dppx<0xB1>(ey); ey += dppx<0x4E>(ey);
    if ((lane & 3) == 0 && hq < NH) {
      f32x2 act;
      act.x = fmaf(sa, 1.f/(1.f + __expf(se*ex)), sb);
      act.y = fmaf(sa, 1.f/(1.f + __expf(se*ey)), sb);
      lq[tb][hq][g] = act;
    }
    __syncthreads();   // the one barrier (lgkm-only drain; no vmem in loop)

    // ---- (f) LSTM cell on pairs ----
    f32x2 gf = lq[tb][hrow][0];
    f32x2 gi = lq[tb][hrow][1];
    f32x2 gg = lq[tb][hrow][2];
    f32x2 go = lq[tb][hrow][3];
    cstate = pk_fma_pp(gf, cstate, pk_mul_pp(gi, gg));
    f32x2 tc; tc.x = tanhr(cstate.x); tc.y = tanhr(cstate.y);
    hval = pk_mul_pp(go, tc);
    if (g == 0 && lane < NH) lhout[t][lane] = hval;   // LDS only (lgkm)
  }

  // ---- bulk coalesced h-output write (off the serial path) ----
  __syncthreads();
  for (int i = tid; i < TS*NH; i += 256) {
    int tt = i / NH, h = i - tt*NH;
    f32x2 hv = lhout[tt][h];
    out[(size_t)tt*(NB*NH) + (size_t)bA*NH + h]       = hv.x;
    out[(size_t)tt*(NB*NH) + (size_t)(bA+1)*NH + h]   = hv.y;
  }
  if (g == 0 && lane < NH) {
    out[(size_t)TS*NB*NH + (size_t)bA*NH + lane]              = hval.x;
    out[(size_t)TS*NB*NH + (size_t)(bA+1)*NH + lane]          = hval.y;
    out[(size_t)TS*NB*NH + NB*NH + (size_t)bA*NH + lane]      = cstate.x;
    out[(size_t)TS*NB*NH + NB*NH + (size_t)(bA+1)*NH + lane]  = cstate.y;
  }
}

extern "C" void kernel_launch(void* const* d_in, const int* in_sizes, int n_in,
                              void* d_out, int out_size, void* d_ws, size_t ws_size,
                              hipStream_t stream) {
  (void)in_sizes; (void)n_in; (void)d_ws; (void)ws_size; (void)out_size;
  qlstm_kernel<<<dim3(NB/2), dim3(256), 0, stream>>>(
      (const float*)d_in[0], (const float*)d_in[1],
      (const float*)d_in[2], (const float*)d_in[3],
      (const float*)d_in[4], (const float*)d_in[5],
      (const float*)d_in[6], (const float*)d_in[7],
      (const float*)d_in[8], (const float*)d_in[9],
      (float*)d_out);
}

// Round 13
// 145.867 us; speedup vs baseline: 1.0613x; 1.0239x over previous
//
#include <hip/hip_runtime.h>

#define TS 64
#define NB 256
#define DI 32
#define NH 10
#define IND 42

typedef float f32x2 __attribute__((ext_vector_type(2)));

// ---- packed-f32 VOP3P helpers. Pair dim = 2 GATES {gA,gB} of one element.
// op_sel[i] selects src-i half for the LO op; op_sel_hi[i] for the HI op;
// neg_lo/neg_hi negate that source in lo/hi. Volatile: R23-proven set.
#define PKOP2(name, instr, mods) \
__device__ __forceinline__ f32x2 name(f32x2 a, f32x2 b){ \
  f32x2 d; asm volatile(instr " %0, %1, %2 " mods : "=v"(d) : "v"(a), "v"(b)); return d; }
#define PKOP3(name, mods) \
__device__ __forceinline__ f32x2 name(f32x2 a, f32x2 b, f32x2 c){ \
  f32x2 d; asm volatile("v_pk_fma_f32 %0, %1, %2, %3 " mods : "=v"(d) : "v"(a), "v"(b), "v"(c)); return d; }

PKOP2(pk_add_p,    "v_pk_add_f32", "op_sel:[0,0] op_sel_hi:[1,1]")                    // {a.l+b.l, a.h+b.h}
PKOP2(pk_sub_p,    "v_pk_add_f32", "op_sel:[0,0] op_sel_hi:[1,1] neg_lo:[0,1] neg_hi:[0,1]") // a-b
PKOP2(pk_mul_pp,   "v_pk_mul_f32", "op_sel:[0,0] op_sel_hi:[1,1]")                    // {a.l*b.l, a.h*b.h}
PKOP2(pk_mul_bl,   "v_pk_mul_f32", "op_sel:[0,0] op_sel_hi:[1,0]")                    // {a.l*b.l, a.h*b.l}
PKOP2(pk_mul_bh,   "v_pk_mul_f32", "op_sel:[0,1] op_sel_hi:[1,1]")                    // {a.l*b.h, a.h*b.h}
PKOP2(pk_mul_bh_na,"v_pk_mul_f32", "op_sel:[0,1] op_sel_hi:[1,1] neg_lo:[1,0] neg_hi:[1,0]") // -a*b.h
PKOP3(pk_fma_pp,   "op_sel:[0,0,0] op_sel_hi:[1,1,1]")                                // a*b + c
PKOP3(pk_fma_na,   "op_sel:[0,0,0] op_sel_hi:[1,1,1] neg_lo:[1,0,0] neg_hi:[1,0,0]")  // -a*b + c
PKOP3(pk_fma_bl,   "op_sel:[0,0,0] op_sel_hi:[1,0,1]")                                // a*b.l + c
PKOP3(pk_fma_bh,   "op_sel:[0,1,0] op_sel_hi:[1,1,1]")                                // a*b.h + c
PKOP3(pk_fma_bh_na,"op_sel:[0,1,0] op_sel_hi:[1,1,1] neg_lo:[1,0,0] neg_hi:[1,0,0]")  // -a*b.h + c
PKOP3(pk_fma_bh_nac,"op_sel:[0,1,0] op_sel_hi:[1,1,1] neg_lo:[1,0,1] neg_hi:[1,0,1]") // -a*b.h - c

// DPP quad_perm xor-exchange: 0xB1 = xor1, 0x4E = xor2 (VALU pipe)
template<int CTRL>
__device__ __forceinline__ float dppx(float v){
  return __int_as_float(__builtin_amdgcn_update_dpp(
      0, __float_as_int(v), CTRL, 0xF, 0xF, true));
}
__device__ __forceinline__ float rl(float v, int lane){
  return __int_as_float(__builtin_amdgcn_readlane(__float_as_int(v), lane));
}
__device__ __forceinline__ f32x2 rl2(f32x2 v, int lane){
  f32x2 r; r.x = rl(v.x, lane); r.y = rl(v.y, lane); return r;
}

__device__ __forceinline__ float tanhr(float x){ float e = __expf(2.f*x); return 1.f - 2.f/(e + 1.f); }

// combined U = RY(t3)*RX(t2)*RZ(t1) -> 8 floats (row0 r/i pairs, row1 r/i pairs)
__device__ __forceinline__ void mkU(float t1, float t2, float t3, float* dst){
  float c1 = __cosf(0.5f*t1), s1 = __sinf(0.5f*t1);
  float c2 = __cosf(0.5f*t2), s2 = __sinf(0.5f*t2);
  float c3 = __cosf(0.5f*t3), s3 = __sinf(0.5f*t3);
  float A00r =  c2*c1, A00i = -c2*s1;
  float A01r =  s2*s1, A01i = -s2*c1;
  float A10r = -s2*s1, A10i = -s2*c1;
  float A11r =  c2*c1, A11i =  c2*s1;
  dst[0] = c3*A00r - s3*A10r; dst[1] = c3*A00i - s3*A10i;
  dst[2] = c3*A01r - s3*A11r; dst[3] = c3*A01i - s3*A11i;
  dst[4] = s3*A00r + c3*A10r; dst[5] = s3*A00i + c3*A10i;
  dst[6] = s3*A01r + c3*A11r; dst[7] = s3*A01i + c3*A11i;
}

__device__ __forceinline__ float3 qf(float q00, float q11, float q01){
  return make_float3(0.5f*(q00+q11), 0.5f*(q00-q11), 0.5f*q01);
}

// R18-verified per-wire map on GATE-pairs; wire consts scalar broadcast:
// Kp={Cp,Cm}, Kq={Cr2,Ci4}, Kr={Ci2,Cr4}. Per-gate rounding == R18 scalar.
__device__ __forceinline__ void wire_step2(f32x2& Q, f32x2& S, f32x2& A, f32x2& B,
    f32x2 vx, f32x2 vy, f32x2 vr, f32x2 vi, f32x2 Kp, f32x2 Kq, f32x2 Kr){
  f32x2 u0 = pk_add_p(Q, A);
  f32x2 u3 = pk_sub_p(Q, A);
  f32x2 m0 = pk_mul_pp(u0, vx);
  f32x2 m3 = pk_mul_pp(u3, vy);
  f32x2 t1 = pk_mul_pp(S, vr);
  f32x2 am = pk_fma_na(B, vi, t1);        // -Bn*vi + S*vr
  f32x2 t2 = pk_mul_pp(S, vi);
  f32x2 bm = pk_fma_pp(B, vr, t2);        //  Bn*vr + S*vi
  f32x2 q2 = pk_add_p(m0, m3);
  f32x2 s2 = pk_sub_p(m0, m3);
  f32x2 am2 = pk_add_p(am, am);
  f32x2 t3 = pk_mul_bl(q2, Kp);           // q2*Cp
  Q = pk_fma_bh(am2, Kp, t3);             // + am2*Cm
  f32x2 t4 = pk_mul_bh(q2, Kp);           // q2*Cm
  S = pk_fma_bl(am2, Kp, t4);             // + am2*Cp
  f32x2 t5 = pk_mul_bh_na(bm, Kq);        // -(bm*Ci4)
  A = pk_fma_bl(s2, Kq, t5);              // s2*Cr2 + t5
  f32x2 t6 = pk_mul_bh(bm, Kr);           // bm*Cr4
  B = pk_fma_bl(s2, Kr, t6);              // s2*Ci2 + t6
}

// R24: 2 GATES PER WAVE (pair dim = gates), block 128 = 2 waves.
// R23 lesson: grid < CU-count wastes wall time (blocks co-resident ->
// wall = per-block time). R24 keeps grid=256, 1 elem/block, but packs
// gates {f,i} into wave0 and {g,o} into wave1: chain constants are
// gate-INDEPENDENT (lBw/K/k-init identical across R20's 4 waves), so the
// packed wire body is the same 19 ops as R20's scalar one. Net: per-wave
// issue ~= R20 + 40 readlanes, but the per-step barrier drops from 4
// waves to 2 (rendezvous+skew halved) and LDS-queue clients halve.
// All instruction constructs are R23-correctness-proven (volatile pk asm,
// scalar ternaries, no pins).
__global__ __launch_bounds__(128) __attribute__((amdgpu_waves_per_eu(1, 1)))
void qlstm_kernel(const float* __restrict__ xin,
                  const float* __restrict__ qp,
                  const float* __restrict__ Wf, const float* __restrict__ bfp,
                  const float* __restrict__ Wi, const float* __restrict__ bip,
                  const float* __restrict__ Wg, const float* __restrict__ bgp,
                  const float* __restrict__ Wo, const float* __restrict__ bop,
                  float* __restrict__ out)
{
  __shared__ float lx[TS][DI + 1];                 // staged x, +1 pad
  __shared__ __align__(8) f32x2 lwx[2][TS][NH];    // W.x+bias gate-pairs
  __shared__ __align__(16) float lBw[NH][4];       // B_w (gate-independent)
  __shared__ __align__(16) f32x2 lq[2][NH][3];     // [buf][h][wavepair(+pad)]
  __shared__ float lhout[TS][NH];                  // buffered h-outputs

  const int tid  = threadIdx.x;
  const int b    = blockIdx.x;
  const int wid  = tid >> 6;         // wave 0: gates {f,i}; wave 1: {g,o}
  const int lane = tid & 63;
  const int hq   = lane >> 2;        // mask index (valid < 10)
  const int sg   = lane & 3;         // 0:sigma0 1:H1 2:H2 3:sigma3
  const int hrow = (lane < NH) ? lane : 0;

  const float* WA = (wid==0) ? Wf  : Wg;
  const float* WB = (wid==0) ? Wi  : Wo;
  const float* bA = (wid==0) ? bfp : bgp;
  const float* bB = (wid==0) ? bip : bop;

  // ---- stage x coalesced ----
  for (int i = tid; i < TS*DI; i += 128) {
    int tt = i >> 5, d = i & 31;
    lx[tt][d] = xin[(size_t)tt*(NB*DI) + b*DI + d];
  }
  // ---- layer-2 B matrices (single copy; wave 0 lanes 0..9) ----
  if (tid < NH) {
    float u[8];
    mkU(qp[30 + tid*3 + 0], qp[30 + tid*3 + 1], qp[30 + tid*3 + 2], u);
    float B00 = u[0]*u[0]+u[1]*u[1] - (u[4]*u[4]+u[5]*u[5]);
    float B11 = u[2]*u[2]+u[3]*u[3] - (u[6]*u[6]+u[7]*u[7]);
    float B01r= u[0]*u[2]+u[1]*u[3] - (u[4]*u[6]+u[5]*u[7]);
    float B01i= u[1]*u[2]-u[0]*u[3] - (u[5]*u[6]-u[4]*u[7]);
    *reinterpret_cast<float4*>(&lBw[tid][0]) = make_float4(B00,B11,B01r,B01i);
  }
  __syncthreads();

  // ---- precompute W.x + bias gate-pairs for all t (lane == t) ----
  {
    float accA[NH], accB[NH];
    #pragma unroll
    for (int h = 0; h < NH; h++) { accA[h] = bA[h]; accB[h] = bB[h]; }
    #pragma unroll
    for (int k = 0; k < DI; k++) {
      float xk = lx[lane][k];
      #pragma unroll
      for (int h = 0; h < NH; h++) {
        accA[h] = fmaf(WA[h*IND + k], xk, accA[h]);
        accB[h] = fmaf(WB[h*IND + k], xk, accB[h]);
      }
    }
    #pragma unroll
    for (int h = 0; h < NH; h++) {
      f32x2 p; p.x = accA[h]; p.y = accB[h];
      lwx[wid][lane][h] = p;
    }
  }

  // ---- recurrent weights, both gates (scalar dots in the loop) ----
  float whA[NH], whB[NH];
  #pragma unroll
  for (int j = 0; j < NH; j++) {
    whA[j] = WA[hrow*IND + DI + j];
    whB[j] = WB[hrow*IND + DI + j];
  }

  // ---- conv-data quadratic forms for wire hrow (gate-independent) ----
  float3 Qn0, Qn1, Qer, Qei;
  {
    float U1[8];
    mkU(qp[hrow*3+0], qp[hrow*3+1], qp[hrow*3+2], U1);
    float r00r=U1[0], r00i=U1[1], r01r=U1[2], r01i=U1[3];
    float r10r=U1[4], r10i=U1[5], r11r=U1[6], r11i=U1[7];
    float P0r,P0i,P1r,P1i, R0r,R0i,R1r,R1i;
    if (lane == 0) {
      P0r=r00r; P0i=r00i; P1r=r01r; P1i=r01i;
      R0r=r10r; R0i=r10i; R1r=r11r; R1i=r11i;
    } else {
      P0r=0.5f*(r00r+r10r); P0i=0.5f*(r00i+r10i);
      P1r=0.5f*(r01r+r11r); P1i=0.5f*(r01i+r11i);
      R0r=0.5f*(r00r-r10r); R0i=0.5f*(r00i-r10i);
      R1r=0.5f*(r01r-r11r); R1i=0.5f*(r01i-r11i);
    }
    Qn0 = qf(P0r*P0r+P0i*P0i, P1r*P1r+P1i*P1i, 2.f*(P0r*P1r+P0i*P1i));
    Qn1 = qf(R0r*R0r+R0i*R0i, R1r*R1r+R1i*R1i, 2.f*(R0r*R1r+R0i*R1i));
    Qer = qf(R0r*P0r+R0i*P0i, R1r*P1r+R1i*P1i,
             (R0r*P1r+R0i*P1i) + (R1r*P0r+R1i*P0i));
    Qei = qf(R0i*P0r-R0r*P0i, R1i*P1r-R1r*P1i,
             (R0i*P1r-R0r*P1i) + (R1i*P0r-R1r*P0i));
  }
  // qeval pairs: value = alpha + beta*C + gamma*S; BG={beta,gamma}, Ax2={a,a}
  f32x2 BGn0, An0, BGn1, An1, BGer, Aer, BGei, Aei;
  BGn0.x=Qn0.y; BGn0.y=Qn0.z; An0.x=Qn0.x; An0.y=Qn0.x;
  BGn1.x=Qn1.y; BGn1.y=Qn1.z; An1.x=Qn1.x; An1.y=Qn1.x;
  BGer.x=Qer.y; BGer.y=Qer.z; Aer.x=Qer.x; Aer.y=Qer.x;
  BGei.x=Qei.y; BGei.y=Qei.z; Aei.x=Qei.x; Aei.y=Qei.x;

  // ---- chain init constants (sg-dep only; identical for both halves) ----
  float4 b0 = *reinterpret_cast<const float4*>(&lBw[0][0]);
  if (hq == 0) b0 = make_float4(1.f, 1.f, 0.f, 0.f);   // E0 mask excludes wire 0
  float k0, k3, ka, kb;
  if      (sg == 0) { k0 = b0.x;  k3 = b0.y;  ka = b0.z; kb = -b0.w; }
  else if (sg == 1) { k0 = b0.z;  k3 = b0.z;  ka = 0.5f*(b0.x + b0.y); kb = 0.f; }
  else if (sg == 2) { k0 = -b0.w; k3 = b0.w;  ka = 0.f;  kb = 0.5f*(b0.y - b0.x); }
  else              { k0 = b0.y;  k3 = b0.x;  ka = b0.z; kb = b0.w; }
  {
    const float gsc = (sg == 0 || sg == 3) ? 0.5f : 1.0f;
    k0 *= gsc; k3 *= gsc; ka *= gsc; kb *= gsc;
  }
  f32x2 KK1, KK2;
  KK1.x = k0;      KK1.y = k3;        // {k0, k3}
  KK2.x = ka + ka; KK2.y = kb + kb;   // {ka2, kb2}

  // ---- per-wire const pairs Kp={Cp,Cm}, Kq={Cr2,Ci4}, Kr={Ci2,Cr4} ----
  f32x2 Kp[9], Kq[9], Kr[9];
  #pragma unroll
  for (int w = 1; w <= 9; w++) {
    float4 bb = *reinterpret_cast<const float4*>(&lBw[w][0]);
    bool inM = (hq == 0) || (w <= hq);        // M_0={1..9}, M_h={0..h}
    float Cpv = inM ? (bb.x + bb.y) : 2.f;
    float Cmv = inM ? (bb.x - bb.y) : 0.f;
    float Cr2 = inM ? (bb.z + bb.z) : 0.f;
    float Ci2 = inM ? (bb.w + bb.w) : 0.f;
    Kp[w-1].x = Cpv;       Kp[w-1].y = Cmv;
    Kq[w-1].x = Cr2;       Kq[w-1].y = Ci2 + Ci2;    // {Cr2, Ci4}
    Kr[w-1].x = Ci2;       Kr[w-1].y = Cr2 + Cr2;    // {Ci2, Cr4}
  }

  // per-half activation constants: only gate 2 (wave1 half A) is tanh
  const int gA = 2*wid, gB = 2*wid + 1;
  const float seA = (gA == 2) ? -2.f : -1.f;
  const float saA = (gA == 2) ?  2.f :  1.f;
  const float sbA = (gA == 2) ? -1.f :  0.f;
  const float seB = (gB == 2) ? -2.f : -1.f;
  const float saB = (gB == 2) ?  2.f :  1.f;
  const float sbB = (gB == 2) ? -1.f :  0.f;

  float cstate = 0.f, hval = 0.f;
  f32x2 wxcur = lwx[wid][0][hrow];    // prefetched W.x pair for t=0

  for (int t = 0; t < TS; t++) {
    const int tb = t & 1;

    // ---- (a) pre-activation, both gates: scalar tree dots ----
    float h0 = rl(hval,0), h1 = rl(hval,1), h2 = rl(hval,2), h3 = rl(hval,3), h4 = rl(hval,4);
    float h5 = rl(hval,5), h6 = rl(hval,6), h7 = rl(hval,7), h8 = rl(hval,8), h9 = rl(hval,9);
    float a0 = fmaf(whA[1], h1, whA[0]*h0);
    float a1 = fmaf(whA[3], h3, whA[2]*h2);
    float a2 = fmaf(whA[5], h5, whA[4]*h4);
    float a3 = fmaf(whA[7], h7, whA[6]*h6);
    float a4 = fmaf(whA[9], h9, whA[8]*h8);
    float preA = wxcur.x + ((a0 + a1) + (a2 + a3) + a4);
    float c0 = fmaf(whB[1], h1, whB[0]*h0);
    float c1 = fmaf(whB[3], h3, whB[2]*h2);
    float c2 = fmaf(whB[5], h5, whB[4]*h4);
    float c3 = fmaf(whB[7], h7, whB[6]*h6);
    float c4 = fmaf(whB[9], h9, whB[8]*h8);
    float preB = wxcur.y + ((c0 + c1) + (c2 + c3) + c4);

    wxcur = lwx[wid][(t+1) & (TS-1)][hrow];   // prefetch next step

    // full-angle sin/cos per gate (|pre| small); 1/2pi scale
    float thA = preA * 0.15915494309189535f;
    float thB = preB * 0.15915494309189535f;
    f32x2 Cc, Ss;
    Cc.x = __builtin_amdgcn_cosf(thA); Cc.y = __builtin_amdgcn_cosf(thB);
    Ss.x = __builtin_amdgcn_sinf(thA); Ss.y = __builtin_amdgcn_sinf(thB);
    f32x2 n0p = pk_fma_bl(Cc, BGn0, pk_fma_bh(Ss, BGn0, An0));
    f32x2 n1p = pk_fma_bl(Cc, BGn1, pk_fma_bh(Ss, BGn1, An1));
    f32x2 erp = pk_fma_bl(Cc, BGer, pk_fma_bh(Ss, BGer, Aer));
    f32x2 eip = pk_fma_bl(Cc, BGei, pk_fma_bh(Ss, BGei, Aei));

    // ---- (c) chain on gate-pairs; v broadcasts via readlane pairs ----
    f32x2 vx0 = rl2(n0p,0), vy0 = rl2(n1p,0), vr0 = rl2(erp,0), vi0 = rl2(eip,0);
    f32x2 t1i = pk_mul_bl(vx0, KK1);             // k0*vx0
    f32x2 Qc  = pk_fma_bh(vy0, KK1, t1i);        // +k3*vy0
    f32x2 Sc  = pk_fma_bh_na(vy0, KK1, t1i);     // -k3*vy0 + t
    f32x2 t2i = pk_mul_bl(vr0, KK2);             // ka2*vr0
    f32x2 Ac  = pk_fma_bh_na(vi0, KK2, t2i);     // -kb2*vi0 + t
    f32x2 t3i = pk_mul_bl(vi0, KK2);             // ka2*vi0
    f32x2 Bc  = pk_fma_bh_nac(vr0, KK2, t3i);    // -kb2*vr0 - t
    #pragma unroll
    for (int w = 1; w <= 9; w++) {
      f32x2 vxw = rl2(n0p, w), vyw = rl2(n1p, w);
      f32x2 vrw = rl2(erp, w), viw = rl2(eip, w);
      wire_step2(Qc, Sc, Ac, Bc, vxw, vyw, vrw, viw, Kp[w-1], Kq[w-1], Kr[w-1]);
    }

    // ---- (d) pick via scalar selects + per-half dpp quad-sum ----
    float QpSx = Qc.x + Sc.x, QpSy = Qc.y + Sc.y;
    float QmSx = Qc.x - Sc.x, QmSy = Qc.y - Sc.y;
    float t0x = (sg & 1) ? Ac.x  : QpSx;
    float t0y = (sg & 1) ? Ac.y  : QpSy;
    float t1x = (sg & 1) ? QmSx : Bc.x;
    float t1y = (sg & 1) ? QmSy : Bc.y;
    float ex = (sg & 2) ? t1x : t0x;
    float ey = (sg & 2) ? t1y : t0y;
    ex += dppx<0xB1>(ex); ex += dppx<0x4E>(ex);
    ey += dppx<0xB1>(ey); ey += dppx<0x4E>(ey);
    if ((lane & 3) == 0 && hq < NH) {
      f32x2 act;
      act.x = fmaf(saA, 1.f/(1.f + __expf(seA*ex)), sbA);
      act.y = fmaf(saB, 1.f/(1.f + __expf(seB*ey)), sbB);
      lq[tb][hq][wid] = act;
    }
    __syncthreads();   // the one barrier: 2 waves only (lgkm-only drain)

    // ---- (f) LSTM cell: {f,i} from wave0 pair, {g,o} from wave1 pair ----
    f32x2 fi = lq[tb][hrow][0];
    f32x2 go = lq[tb][hrow][1];
    cstate = fmaf(fi.x, cstate, fi.y*go.x);
    hval = go.y*tanhr(cstate);
    if (wid == 0 && lane < NH) lhout[t][lane] = hval;   // LDS only (lgkm)
  }

  // ---- bulk coalesced h-output write (off the serial path) ----
  __syncthreads();
  for (int i = tid; i < TS*NH; i += 128) {
    int tt = i / NH, h = i - tt*NH;
    out[(size_t)tt*(NB*NH) + b*NH + h] = lhout[tt][h];
  }
  if (wid == 0 && lane < NH) {
    out[(size_t)TS*NB*NH + b*NH + lane]          = hval;
    out[(size_t)TS*NB*NH + NB*NH + b*NH + lane]  = cstate;
  }
}

extern "C" void kernel_launch(void* const* d_in, const int* in_sizes, int n_in,
                              void* d_out, int out_size, void* d_ws, size_t ws_size,
                              hipStream_t stream) {
  (void)in_sizes; (void)n_in; (void)d_ws; (void)ws_size; (void)out_size;
  qlstm_kernel<<<dim3(NB), dim3(128), 0, stream>>>(
      (const float*)d_in[0], (const float*)d_in[1],
      (const float*)d_in[2], (const float*)d_in[3],
      (const float*)d_in[4], (const float*)d_in[5],
      (const float*)d_in[6], (const float*)d_in[7],
      (const float*)d_in[8], (const float*)d_in[9],
      (float*)d_out);
}

// Round 15
// 134.302 us; speedup vs baseline: 1.1527x; 1.0861x over previous
//
#include <hip/hip_runtime.h>

#define TS 64
#define NB 256
#define DI 32
#define NH 10
#define IND 42

typedef float f32x2 __attribute__((ext_vector_type(2)));

// ---- R26: NO inline asm in the chain. gfx950 has packed fp32 VALU ops and
// LLVM selects v_pk_{add,mul,fma}_f32 from <2 x float> IR directly. Plain
// vector C gives compiler-guaranteed semantics (R22/R25's non-volatile asm
// was miscompiled; volatile asm (R23/R24) was order-pinned to ~80us).
__device__ __forceinline__ f32x2 bc(float s){ f32x2 r; r.x = s; r.y = s; return r; }
__device__ __forceinline__ f32x2 fma2(f32x2 a, f32x2 b, f32x2 c){
#if __has_builtin(__builtin_elementwise_fma)
  return __builtin_elementwise_fma(a, b, c);
#else
  f32x2 r; r.x = __builtin_fmaf(a.x, b.x, c.x); r.y = __builtin_fmaf(a.y, b.y, c.y); return r;
#endif
}

// DPP quad_perm xor-exchange: 0xB1 = xor1, 0x4E = xor2 (VALU pipe)
template<int CTRL>
__device__ __forceinline__ float dppx(float v){
  return __int_as_float(__builtin_amdgcn_update_dpp(
      0, __float_as_int(v), CTRL, 0xF, 0xF, true));
}
__device__ __forceinline__ float rl(float v, int lane){
  return __int_as_float(__builtin_amdgcn_readlane(__float_as_int(v), lane));
}
__device__ __forceinline__ f32x2 rl2(f32x2 v, int lane){
  f32x2 r; r.x = rl(v.x, lane); r.y = rl(v.y, lane); return r;
}

__device__ __forceinline__ float tanhr(float x){ float e = __expf(2.f*x); return 1.f - 2.f/(e + 1.f); }

// combined U = RY(t3)*RX(t2)*RZ(t1) -> 8 floats (row0 r/i pairs, row1 r/i pairs)
__device__ __forceinline__ void mkU(float t1, float t2, float t3, float* dst){
  float c1 = __cosf(0.5f*t1), s1 = __sinf(0.5f*t1);
  float c2 = __cosf(0.5f*t2), s2 = __sinf(0.5f*t2);
  float c3 = __cosf(0.5f*t3), s3 = __sinf(0.5f*t3);
  float A00r =  c2*c1, A00i = -c2*s1;
  float A01r =  s2*s1, A01i = -s2*c1;
  float A10r = -s2*s1, A10i = -s2*c1;
  float A11r =  c2*c1, A11i =  c2*s1;
  dst[0] = c3*A00r - s3*A10r; dst[1] = c3*A00i - s3*A10i;
  dst[2] = c3*A01r - s3*A11r; dst[3] = c3*A01i - s3*A11i;
  dst[4] = s3*A00r + c3*A10r; dst[5] = s3*A00i + c3*A10i;
  dst[6] = s3*A01r + c3*A11r; dst[7] = s3*A01i + c3*A11i;
}

__device__ __forceinline__ float3 qf(float q00, float q11, float q01){
  return make_float3(0.5f*(q00+q11), 0.5f*(q00-q11), 0.5f*q01);
}

// R18-verified per-wire map on GATE-pairs, portable-vector form.
// Op-for-op identical to the R23/R24 HW-verified sequence:
//   am = -B*vi + S*vr ; bm = B*vr + S*vi
//   Q' = am2*Cm + q2*Cp ; S' = am2*Cp + q2*Cm
//   A' = s2*Cr2 - bm*Ci4 ; B' = s2*Ci2 + bm*Cr4
__device__ __forceinline__ void wire_step2(f32x2& Q, f32x2& S, f32x2& A, f32x2& B,
    f32x2 vx, f32x2 vy, f32x2 vr, f32x2 vi,
    float Cp, float Cm, float Cr2, float Ci4, float Ci2, float Cr4){
  f32x2 u0 = Q + A;
  f32x2 u3 = Q - A;
  f32x2 m0 = u0 * vx;
  f32x2 m3 = u3 * vy;
  f32x2 am = fma2(-B, vi, S * vr);
  f32x2 bm = fma2( B, vr, S * vi);
  f32x2 q2 = m0 + m3;
  f32x2 s2 = m0 - m3;
  f32x2 am2 = am + am;
  Q = fma2(am2, bc(Cm), q2 * bc(Cp));
  S = fma2(am2, bc(Cp), q2 * bc(Cm));
  A = fma2(s2, bc(Cr2), -(bm * bc(Ci4)));
  B = fma2(s2, bc(Ci2), bm * bc(Cr4));
}

// R26: R24/R25's 2-gates-per-wave structure (block 128 = 2 waves, half the
// barrier participants of R20), chain in portable vector C (see above).
// Structure HW-verified correct in R24; math HW-verified in R23; this swaps
// only the codegen path (compiler-selected v_pk ops, full sched freedom).
// Clean A/B vs R20: 2 barrier participants vs 4, issue ~R20-level.
__global__ __launch_bounds__(128) __attribute__((amdgpu_waves_per_eu(1, 1)))
void qlstm_kernel(const float* __restrict__ xin,
                  const float* __restrict__ qp,
                  const float* __restrict__ Wf, const float* __restrict__ bfp,
                  const float* __restrict__ Wi, const float* __restrict__ bip,
                  const float* __restrict__ Wg, const float* __restrict__ bgp,
                  const float* __restrict__ Wo, const float* __restrict__ bop,
                  float* __restrict__ out)
{
  __shared__ float lx[TS][DI + 1];                 // staged x, +1 pad
  __shared__ __align__(8) f32x2 lwx[2][TS][NH];    // W.x+bias gate-pairs
  __shared__ __align__(16) float lBw[NH][4];       // B_w (gate-independent)
  __shared__ __align__(16) float lq[2][NH][4];     // [buf][h][gate] -> b128
  __shared__ float lhout[TS][NH];                  // buffered h-outputs

  const int tid  = threadIdx.x;
  const int b    = blockIdx.x;
  const int wid  = tid >> 6;         // wave 0: gates {f,i}; wave 1: {g,o}
  const int lane = tid & 63;
  const int hq   = lane >> 2;        // mask index (valid < 10)
  const int sg   = lane & 3;         // 0:sigma0 1:H1 2:H2 3:sigma3
  const int hrow = (lane < NH) ? lane : 0;

  const float* WA = (wid==0) ? Wf  : Wg;
  const float* WB = (wid==0) ? Wi  : Wo;
  const float* bA = (wid==0) ? bfp : bgp;
  const float* bB = (wid==0) ? bip : bop;

  // ---- stage x coalesced ----
  for (int i = tid; i < TS*DI; i += 128) {
    int tt = i >> 5, d = i & 31;
    lx[tt][d] = xin[(size_t)tt*(NB*DI) + b*DI + d];
  }
  // ---- layer-2 B matrices (single copy; wave 0 lanes 0..9) ----
  if (tid < NH) {
    float u[8];
    mkU(qp[30 + tid*3 + 0], qp[30 + tid*3 + 1], qp[30 + tid*3 + 2], u);
    float B00 = u[0]*u[0]+u[1]*u[1] - (u[4]*u[4]+u[5]*u[5]);
    float B11 = u[2]*u[2]+u[3]*u[3] - (u[6]*u[6]+u[7]*u[7]);
    float B01r= u[0]*u[2]+u[1]*u[3] - (u[4]*u[6]+u[5]*u[7]);
    float B01i= u[1]*u[2]-u[0]*u[3] - (u[5]*u[6]-u[4]*u[7]);
    *reinterpret_cast<float4*>(&lBw[tid][0]) = make_float4(B00,B11,B01r,B01i);
  }
  __syncthreads();

  // ---- precompute W.x + bias gate-pairs for all t (lane == t) ----
  {
    float accA[NH], accB[NH];
    #pragma unroll
    for (int h = 0; h < NH; h++) { accA[h] = bA[h]; accB[h] = bB[h]; }
    #pragma unroll
    for (int k = 0; k < DI; k++) {
      float xk = lx[lane][k];
      #pragma unroll
      for (int h = 0; h < NH; h++) {
        accA[h] = fmaf(WA[h*IND + k], xk, accA[h]);
        accB[h] = fmaf(WB[h*IND + k], xk, accB[h]);
      }
    }
    #pragma unroll
    for (int h = 0; h < NH; h++) {
      f32x2 p; p.x = accA[h]; p.y = accB[h];
      lwx[wid][lane][h] = p;
    }
  }

  // ---- recurrent weights, both gates (scalar dots in the loop) ----
  float whA[NH], whB[NH];
  #pragma unroll
  for (int j = 0; j < NH; j++) {
    whA[j] = WA[hrow*IND + DI + j];
    whB[j] = WB[hrow*IND + DI + j];
  }

  // ---- conv-data quadratic forms for wire hrow (gate-independent) ----
  float3 Qn0, Qn1, Qer, Qei;
  {
    float U1[8];
    mkU(qp[hrow*3+0], qp[hrow*3+1], qp[hrow*3+2], U1);
    float r00r=U1[0], r00i=U1[1], r01r=U1[2], r01i=U1[3];
    float r10r=U1[4], r10i=U1[5], r11r=U1[6], r11i=U1[7];
    float P0r,P0i,P1r,P1i, R0r,R0i,R1r,R1i;
    if (lane == 0) {
      P0r=r00r; P0i=r00i; P1r=r01r; P1i=r01i;
      R0r=r10r; R0i=r10i; R1r=r11r; R1i=r11i;
    } else {
      P0r=0.5f*(r00r+r10r); P0i=0.5f*(r00i+r10i);
      P1r=0.5f*(r01r+r11r); P1i=0.5f*(r01i+r11i);
      R0r=0.5f*(r00r-r10r); R0i=0.5f*(r00i-r10i);
      R1r=0.5f*(r01r-r11r); R1i=0.5f*(r01i-r11i);
    }
    Qn0 = qf(P0r*P0r+P0i*P0i, P1r*P1r+P1i*P1i, 2.f*(P0r*P1r+P0i*P1i));
    Qn1 = qf(R0r*R0r+R0i*R0i, R1r*R1r+R1i*R1i, 2.f*(R0r*R1r+R0i*R1i));
    Qer = qf(R0r*P0r+R0i*P0i, R1r*P1r+R1i*P1i,
             (R0r*P1r+R0i*P1i) + (R1r*P0r+R1i*P0i));
    Qei = qf(R0i*P0r-R0r*P0i, R1i*P1r-R1r*P1i,
             (R0i*P1r-R0r*P1i) + (R1i*P0r-R1r*P0i));
  }

  // ---- chain init constants (sg-dep only; identical for both halves) ----
  float4 b0 = *reinterpret_cast<const float4*>(&lBw[0][0]);
  if (hq == 0) b0 = make_float4(1.f, 1.f, 0.f, 0.f);   // E0 mask excludes wire 0
  float k0, k3, ka, kb;
  if      (sg == 0) { k0 = b0.x;  k3 = b0.y;  ka = b0.z; kb = -b0.w; }
  else if (sg == 1) { k0 = b0.z;  k3 = b0.z;  ka = 0.5f*(b0.x + b0.y); kb = 0.f; }
  else if (sg == 2) { k0 = -b0.w; k3 = b0.w;  ka = 0.f;  kb = 0.5f*(b0.y - b0.x); }
  else              { k0 = b0.y;  k3 = b0.x;  ka = b0.z; kb = b0.w; }
  {
    const float gsc = (sg == 0 || sg == 3) ? 0.5f : 1.0f;
    k0 *= gsc; k3 *= gsc; ka *= gsc; kb *= gsc;
  }
  const float ka2 = ka + ka, kb2 = kb + kb;

  // ---- per-wire scalar constants (mask by hq) ----
  float Cp_[9], Cm_[9], Cr2_[9], Ci4_[9], Ci2_[9], Cr4_[9];
  #pragma unroll
  for (int w = 1; w <= 9; w++) {
    float4 bb = *reinterpret_cast<const float4*>(&lBw[w][0]);
    bool inM = (hq == 0) || (w <= hq);        // M_0={1..9}, M_h={0..h}
    float Cpv = inM ? (bb.x + bb.y) : 2.f;
    float Cmv = inM ? (bb.x - bb.y) : 0.f;
    float Cr2 = inM ? (bb.z + bb.z) : 0.f;
    float Ci2 = inM ? (bb.w + bb.w) : 0.f;
    Cp_[w-1]  = Cpv;
    Cm_[w-1]  = Cmv;
    Cr2_[w-1] = Cr2;
    Ci4_[w-1] = Ci2 + Ci2;
    Ci2_[w-1] = Ci2;
    Cr4_[w-1] = Cr2 + Cr2;
  }

  // per-half activation constants: only gate 2 (wave1 half A) is tanh
  const int gA = 2*wid, gB = 2*wid + 1;
  const float seA = (gA == 2) ? -2.f : -1.f;
  const float saA = (gA == 2) ?  2.f :  1.f;
  const float sbA = (gA == 2) ? -1.f :  0.f;
  const float seB = (gB == 2) ? -2.f : -1.f;
  const float saB = (gB == 2) ?  2.f :  1.f;
  const float sbB = (gB == 2) ? -1.f :  0.f;

  float cstate = 0.f, hval = 0.f;
  f32x2 wxcur = lwx[wid][0][hrow];    // prefetched W.x pair for t=0

  for (int t = 0; t < TS; t++) {
    const int tb = t & 1;

    // ---- (a) pre-activation, both gates: scalar tree dots ----
    float h0 = rl(hval,0), h1 = rl(hval,1), h2 = rl(hval,2), h3 = rl(hval,3), h4 = rl(hval,4);
    float h5 = rl(hval,5), h6 = rl(hval,6), h7 = rl(hval,7), h8 = rl(hval,8), h9 = rl(hval,9);
    float a0 = fmaf(whA[1], h1, whA[0]*h0);
    float a1 = fmaf(whA[3], h3, whA[2]*h2);
    float a2 = fmaf(whA[5], h5, whA[4]*h4);
    float a3 = fmaf(whA[7], h7, whA[6]*h6);
    float a4 = fmaf(whA[9], h9, whA[8]*h8);
    float preA = wxcur.x + ((a0 + a1) + (a2 + a3) + a4);
    float c0 = fmaf(whB[1], h1, whB[0]*h0);
    float c1 = fmaf(whB[3], h3, whB[2]*h2);
    float c2 = fmaf(whB[5], h5, whB[4]*h4);
    float c3 = fmaf(whB[7], h7, whB[6]*h6);
    float c4 = fmaf(whB[9], h9, whB[8]*h8);
    float preB = wxcur.y + ((c0 + c1) + (c2 + c3) + c4);

    wxcur = lwx[wid][(t+1) & (TS-1)][hrow];   // prefetch next step

    // full-angle sin/cos per gate (|pre| small); 1/2pi scale
    float thA = preA * 0.15915494309189535f;
    float thB = preB * 0.15915494309189535f;
    f32x2 Cc, Ss;
    Cc.x = __builtin_amdgcn_cosf(thA); Cc.y = __builtin_amdgcn_cosf(thB);
    Ss.x = __builtin_amdgcn_sinf(thA); Ss.y = __builtin_amdgcn_sinf(thB);
    f32x2 n0p = fma2(Cc, bc(Qn0.y), fma2(Ss, bc(Qn0.z), bc(Qn0.x)));
    f32x2 n1p = fma2(Cc, bc(Qn1.y), fma2(Ss, bc(Qn1.z), bc(Qn1.x)));
    f32x2 erp = fma2(Cc, bc(Qer.y), fma2(Ss, bc(Qer.z), bc(Qer.x)));
    f32x2 eip = fma2(Cc, bc(Qei.y), fma2(Ss, bc(Qei.z), bc(Qei.x)));

    // ---- (c) chain on gate-pairs; v broadcasts via readlane pairs ----
    f32x2 vx0 = rl2(n0p,0), vy0 = rl2(n1p,0), vr0 = rl2(erp,0), vi0 = rl2(eip,0);
    f32x2 t1i = vx0 * bc(k0);                 // k0*vx0
    f32x2 Qc  = fma2(vy0, bc(k3), t1i);       // +k3*vy0
    f32x2 Sc  = fma2(-vy0, bc(k3), t1i);      // -k3*vy0 + t
    f32x2 t2i = vr0 * bc(ka2);                // ka2*vr0
    f32x2 Ac  = fma2(-vi0, bc(kb2), t2i);     // -kb2*vi0 + t
    f32x2 t3i = vi0 * bc(ka2);                // ka2*vi0
    f32x2 Bc  = fma2(-vr0, bc(kb2), -t3i);    // -kb2*vr0 - t
    #pragma unroll
    for (int w = 1; w <= 9; w++) {
      f32x2 vxw = rl2(n0p, w), vyw = rl2(n1p, w);
      f32x2 vrw = rl2(erp, w), viw = rl2(eip, w);
      wire_step2(Qc, Sc, Ac, Bc, vxw, vyw, vrw, viw,
                 Cp_[w-1], Cm_[w-1], Cr2_[w-1], Ci4_[w-1], Ci2_[w-1], Cr4_[w-1]);
    }

    // ---- (d) pick via scalar selects + per-half dpp quad-sum ----
    float QpSx = Qc.x + Sc.x, QpSy = Qc.y + Sc.y;
    float QmSx = Qc.x - Sc.x, QmSy = Qc.y - Sc.y;
    float t0x = (sg & 1) ? Ac.x  : QpSx;
    float t0y = (sg & 1) ? Ac.y  : QpSy;
    float t1x = (sg & 1) ? QmSx : Bc.x;
    float t1y = (sg & 1) ? QmSy : Bc.y;
    float ex = (sg & 2) ? t1x : t0x;
    float ey = (sg & 2) ? t1y : t0y;
    ex += dppx<0xB1>(ex); ex += dppx<0x4E>(ex);
    ey += dppx<0xB1>(ey); ey += dppx<0x4E>(ey);
    if ((lane & 3) == 0 && hq < NH) {
      float actA = fmaf(saA, 1.f/(1.f + __expf(seA*ex)), sbA);
      float actB = fmaf(saB, 1.f/(1.f + __expf(seB*ey)), sbB);
      lq[tb][hq][2*wid]     = actA;
      lq[tb][hq][2*wid + 1] = actB;
    }
    __syncthreads();   // the one barrier: 2 waves only (lgkm-only drain)

    // ---- (f) LSTM cell: single b128 broadcast read of (f,i,g,o) ----
    float4 gates = *reinterpret_cast<const float4*>(&lq[tb][hrow][0]);
    cstate = fmaf(gates.x, cstate, gates.y*gates.z);
    hval = gates.w*tanhr(cstate);
    if (wid == 0 && lane < NH) lhout[t][lane] = hval;   // LDS only (lgkm)
  }

  // ---- bulk coalesced h-output write (off the serial path) ----
  __syncthreads();
  for (int i = tid; i < TS*NH; i += 128) {
    int tt = i / NH, h = i - tt*NH;
    out[(size_t)tt*(NB*NH) + b*NH + h] = lhout[tt][h];
  }
  if (wid == 0 && lane < NH) {
    out[(size_t)TS*NB*NH + b*NH + lane]          = hval;
    out[(size_t)TS*NB*NH + NB*NH + b*NH + lane]  = cstate;
  }
}

extern "C" void kernel_launch(void* const* d_in, const int* in_sizes, int n_in,
                              void* d_out, int out_size, void* d_ws, size_t ws_size,
                              hipStream_t stream) {
  (void)in_sizes; (void)n_in; (void)d_ws; (void)ws_size; (void)out_size;
  qlstm_kernel<<<dim3(NB), dim3(128), 0, stream>>>(
      (const float*)d_in[0], (const float*)d_in[1],
      (const float*)d_in[2], (const float*)d_in[3],
      (const float*)d_in[4], (const float*)d_in[5],
      (const float*)d_in[6], (const float*)d_in[7],
      (const float*)d_in[8], (const float*)d_in[9],
      (float*)d_out);
}

// Round 16
// 119.000 us; speedup vs baseline: 1.3009x; 1.1286x over previous
//
#include <hip/hip_runtime.h>

#define TS 64
#define NB 256
#define DI 32
#define NH 10
#define IND 42

typedef float f32x2 __attribute__((ext_vector_type(2)));

// ---- packed-f32 VOP3P helpers (CDNA2+). op_sel[i]: which half of src i
// feeds the LO op; op_sel_hi[i]: which half feeds the HI op. neg_lo/neg_hi
// negate that source in the lo/hi op. All derived+checked vs scalar R18.
// NON-volatile: this exact set is HW-verified correct (R19/R20).
#define PKOP2(name, instr, mods) \
__device__ __forceinline__ f32x2 name(f32x2 a, f32x2 b){ \
  f32x2 d; asm(instr " %0, %1, %2 " mods : "=v"(d) : "v"(a), "v"(b)); return d; }
#define PKOP3(name, mods) \
__device__ __forceinline__ f32x2 name(f32x2 a, f32x2 b, f32x2 c){ \
  f32x2 d; asm("v_pk_fma_f32 %0, %1, %2, %3 " mods : "=v"(d) : "v"(a), "v"(b), "v"(c)); return d; }

PKOP2(pk_mul,       "v_pk_mul_f32", "op_sel:[0,0] op_sel_hi:[1,1]")                 // {a.l*b.l, a.h*b.h}
PKOP2(pk_mul_s0hi,  "v_pk_mul_f32", "op_sel:[1,0] op_sel_hi:[1,1]")                 // {a.h*b.l, a.h*b.h}
PKOP2(pk_mul_s0lo,  "v_pk_mul_f32", "op_sel:[0,0] op_sel_hi:[0,1]")                 // {a.l*b.l, a.l*b.h}
PKOP2(pk_mul_s1lo,  "v_pk_mul_f32", "op_sel:[0,0] op_sel_hi:[1,0]")                 // {a.l*b.l, a.h*b.l}
PKOP2(pk_addsub_ll, "v_pk_add_f32", "op_sel:[0,0] op_sel_hi:[0,0] neg_hi:[0,1]")    // {a.l+b.l, a.l-b.l}
PKOP2(pk_addsub_lh, "v_pk_add_f32", "op_sel:[0,1] op_sel_hi:[0,1] neg_hi:[0,1]")    // {a.l+b.h, a.l-b.h}
PKOP3(pk_fma_s1lo,  "op_sel:[0,0,0] op_sel_hi:[1,0,1]")                // {a.l*b.l+c.l, a.h*b.l+c.h}
PKOP3(pk_fma_s1hi,  "op_sel:[0,1,0] op_sel_hi:[1,1,1]")                // {a.l*b.h+c.l, a.h*b.h+c.h}
PKOP3(pk_fma_s1swap,"op_sel:[0,1,0] op_sel_hi:[1,0,1]")                // {a.l*b.h+c.l, a.h*b.l+c.h}
PKOP3(pk_fma_am,    "op_sel:[1,1,0] op_sel_hi:[1,0,1] neg_lo:[1,0,0]") // {-a.h*b.h+c.l, a.h*b.l+c.h}
PKOP3(pk_fma_s0lo,  "op_sel:[0,0,0] op_sel_hi:[0,1,1]")                // {a.l*b.l+c.l, a.l*b.h+c.h}
PKOP3(pk_fma_s0hi,  "op_sel:[1,0,0] op_sel_hi:[1,1,1]")                // {a.h*b.l+c.l, a.h*b.h+c.h}

// DPP quad_perm xor-exchange: 0xB1 = xor1, 0x4E = xor2 (VALU pipe)
template<int CTRL>
__device__ __forceinline__ float dppx(float v){
  return __int_as_float(__builtin_amdgcn_update_dpp(
      0, __float_as_int(v), CTRL, 0xF, 0xF, true));
}
__device__ __forceinline__ float rl(float v, int lane){
  return __int_as_float(__builtin_amdgcn_readlane(__float_as_int(v), lane));
}
// broadcast both halves of a pair from a fixed lane
__device__ __forceinline__ f32x2 rl2(f32x2 v, int lane){
  f32x2 r; r.x = rl(v.x, lane); r.y = rl(v.y, lane); return r;
}
__device__ __forceinline__ void pin(float& x){ asm volatile("" : "+v"(x)); }
__device__ __forceinline__ void pinv(f32x2& x){ asm volatile("" : "+v"(x)); }

__device__ __forceinline__ float tanhr(float x){ float e = __expf(2.f*x); return 1.f - 2.f/(e + 1.f); }

// combined U = RY(t3)*RX(t2)*RZ(t1) -> 8 floats (row0 r/i pairs, row1 r/i pairs)
__device__ __forceinline__ void mkU(float t1, float t2, float t3, float* dst){
  float c1 = __cosf(0.5f*t1), s1 = __sinf(0.5f*t1);
  float c2 = __cosf(0.5f*t2), s2 = __sinf(0.5f*t2);
  float c3 = __cosf(0.5f*t3), s3 = __sinf(0.5f*t3);
  float A00r =  c2*c1, A00i = -c2*s1;
  float A01r =  s2*s1, A01i = -s2*c1;
  float A10r = -s2*s1, A10i = -s2*c1;
  float A11r =  c2*c1, A11i =  c2*s1;
  dst[0] = c3*A00r - s3*A10r; dst[1] = c3*A00i - s3*A10i;
  dst[2] = c3*A01r - s3*A11r; dst[3] = c3*A01i - s3*A11i;
  dst[4] = s3*A00r + c3*A10r; dst[5] = s3*A00i + c3*A10i;
  dst[6] = s3*A01r + c3*A11r; dst[7] = s3*A01i + c3*A11i;
}

__device__ __forceinline__ float3 qf(float q00, float q11, float q01){
  return make_float3(0.5f*(q00+q11), 0.5f*(q00-q11), 0.5f*q01);
}

// R27 = R20 verbatim (session optimum: 117.3us bench / 52.2us dispatch).
// Final post-mortem across R14-R26 established the additive latency model:
// with 1 wave/SIMD, step wall ~= per-wave issue (~950cyc) + exposed serial
// latency (~1000cyc: chain deps + 4-gate LDS exchange + barrier + trans).
// All structural alternatives measured worse: 2-elem coupling (+59-60%),
// 1-wave/0-barrier (+73%), 2-gates-per-wave (+33-53%); issue cuts beyond
// R18 are absorbed by latency. The two real wins are in here: no vmem in
// the t-loop (barrier never drains HBM stores; h buffered in LDS) and
// full register residency of chain constants (waves_per_eu(1,1) + pins).
__global__ __launch_bounds__(256) __attribute__((amdgpu_waves_per_eu(1, 1)))
void qlstm_kernel(const float* __restrict__ xin,
                  const float* __restrict__ qp,
                  const float* __restrict__ Wf, const float* __restrict__ bfp,
                  const float* __restrict__ Wi, const float* __restrict__ bip,
                  const float* __restrict__ Wg, const float* __restrict__ bgp,
                  const float* __restrict__ Wo, const float* __restrict__ bop,
                  float* __restrict__ out)
{
  __shared__ float lx[TS][DI + 1];                // staged x, +1 pad
  __shared__ float lwx[4][TS][NH];                // precomputed W.x + bias
  __shared__ __align__(16) float lBw[4][NH][4];   // B_w = U2^dag Z U2
  __shared__ __align__(16) float lq[2][NH][4];    // [buf][h][gate] -> b128 read
  __shared__ float lhout[TS][NH];                 // buffered h-outputs

  const int tid  = threadIdx.x;
  const int b    = blockIdx.x;
  const int g    = tid >> 6;
  const int lane = tid & 63;
  const int hq   = lane >> 2;        // mask index (valid < 10)
  const int sg   = lane & 3;         // 0:sigma0 1:H1 2:H2 3:sigma3
  const int hrow = (lane < NH) ? lane : 0;

  const float* Wsel = (g==0) ? Wf : (g==1) ? Wi : (g==2) ? Wg : Wo;
  const float* bsel = (g==0) ? bfp : (g==1) ? bip : (g==2) ? bgp : bop;

  // ---- stage x coalesced ----
  for (int i = tid; i < TS*DI; i += 256) {
    int tt = i >> 5, d = i & 31;
    lx[tt][d] = xin[(size_t)tt*(NB*DI) + b*DI + d];
  }
  // ---- layer-2 B matrices ----
  if (lane < NH) {
    float u[8];
    mkU(qp[30 + lane*3 + 0], qp[30 + lane*3 + 1], qp[30 + lane*3 + 2], u);
    float B00 = u[0]*u[0]+u[1]*u[1] - (u[4]*u[4]+u[5]*u[5]);
    float B11 = u[2]*u[2]+u[3]*u[3] - (u[6]*u[6]+u[7]*u[7]);
    float B01r= u[0]*u[2]+u[1]*u[3] - (u[4]*u[6]+u[5]*u[7]);
    float B01i= u[1]*u[2]-u[0]*u[3] - (u[5]*u[6]-u[4]*u[7]);
    *reinterpret_cast<float4*>(&lBw[g][lane][0]) = make_float4(B00,B11,B01r,B01i);
  }
  __syncthreads();

  // ---- precompute W.x + bias for all t (lane == t), wave-private lwx[g] ----
  {
    float acc[NH];
    #pragma unroll
    for (int h = 0; h < NH; h++) acc[h] = bsel[h];
    #pragma unroll
    for (int k = 0; k < DI; k++) {
      float xk = lx[lane][k];
      #pragma unroll
      for (int h = 0; h < NH; h++) acc[h] = fmaf(Wsel[h*IND + k], xk, acc[h]);
    }
    #pragma unroll
    for (int h = 0; h < NH; h++) lwx[g][lane][h] = acc[h];
  }

  // ---- register-resident recurrent weights + conv-data quadratic forms ----
  float wh[NH];
  #pragma unroll
  for (int j = 0; j < NH; j++) wh[j] = Wsel[hrow*IND + DI + j];

  float3 Qn0, Qn1, Qer, Qei;
  {
    float U1[8];
    mkU(qp[hrow*3+0], qp[hrow*3+1], qp[hrow*3+2], U1);
    float r00r=U1[0], r00i=U1[1], r01r=U1[2], r01i=U1[3];
    float r10r=U1[4], r10i=U1[5], r11r=U1[6], r11i=U1[7];
    float P0r,P0i,P1r,P1i, R0r,R0i,R1r,R1i;
    if (lane == 0) {
      P0r=r00r; P0i=r00i; P1r=r01r; P1i=r01i;
      R0r=r10r; R0i=r10i; R1r=r11r; R1i=r11i;
    } else {
      P0r=0.5f*(r00r+r10r); P0i=0.5f*(r00i+r10i);
      P1r=0.5f*(r01r+r11r); P1i=0.5f*(r01i+r11i);
      R0r=0.5f*(r00r-r10r); R0i=0.5f*(r00i-r10i);
      R1r=0.5f*(r01r-r11r); R1i=0.5f*(r01i-r11i);
    }
    Qn0 = qf(P0r*P0r+P0i*P0i, P1r*P1r+P1i*P1i, 2.f*(P0r*P1r+P0i*P1i));
    Qn1 = qf(R0r*R0r+R0i*R0i, R1r*R1r+R1i*R1i, 2.f*(R0r*R1r+R0i*R1i));
    Qer = qf(R0r*P0r+R0i*P0i, R1r*P1r+R1i*P1i,
             (R0r*P1r+R0i*P1i) + (R1r*P0r+R1i*P0i));
    Qei = qf(R0i*P0r-R0r*P0i, R1i*P1r-R1r*P1i,
             (R0i*P1r-R0r*P1i) + (R1i*P0r-R1r*P0i));
  }
  // pairs for the packed qeval: value = alpha + beta*C + gamma*S
  f32x2 QnA, QnB, QnG, QeA, QeB, QeG;
  QnA.x=Qn0.x; QnA.y=Qn1.x;  QnB.x=Qn0.y; QnB.y=Qn1.y;  QnG.x=Qn0.z; QnG.y=Qn1.z;
  QeA.x=Qer.x; QeA.y=Qei.x;  QeB.x=Qer.y; QeB.y=Qei.y;  QeG.x=Qer.z; QeG.y=Qei.z;

  // ---- per-lane chain init constants; pick scale folded in via linearity ----
  float4 b0 = *reinterpret_cast<const float4*>(&lBw[g][0][0]);
  if (hq == 0) b0 = make_float4(1.f, 1.f, 0.f, 0.f);   // E0 mask excludes wire 0
  float k0, k3, ka, kb;
  if      (sg == 0) { k0 = b0.x;  k3 = b0.y;  ka = b0.z; kb = -b0.w; }
  else if (sg == 1) { k0 = b0.z;  k3 = b0.z;  ka = 0.5f*(b0.x + b0.y); kb = 0.f; }
  else if (sg == 2) { k0 = -b0.w; k3 = b0.w;  ka = 0.f;  kb = 0.5f*(b0.y - b0.x); }
  else              { k0 = b0.y;  k3 = b0.x;  ka = b0.z; kb = b0.w; }
  {
    const float gsc = (sg == 0 || sg == 3) ? 0.5f : 1.0f;
    k0 *= gsc; k3 *= gsc; ka *= gsc; kb *= gsc;
  }
  const float ka2 = ka + ka, kb2 = kb + kb;
  f32x2 KA, KB, KC, KD;
  KA.x = k0;   KA.y = k0;
  KB.x = k3;   KB.y = -k3;
  KC.x = ka2;  KC.y = -ka2;
  KD.x = -kb2; KD.y = -kb2;

  // ---- per-wire packed constants ----
  // K1={Cp,Cm} K2={2Cm,2Cp} K3={Cr2,Ci2} K4={-Ci4,Cr4}; masked: {2,0},{0,4},0,0
  f32x2 K1[9], K2[9], K3[9], K4[9];
  #pragma unroll
  for (int w = 1; w <= 9; w++) {
    float4 bb = *reinterpret_cast<const float4*>(&lBw[g][w][0]);
    bool inM = (hq == 0) || (w <= hq);        // M_0={1..9}, M_h={0..h}
    float Cp = inM ? (bb.x + bb.y) : 2.f;
    float Cm = inM ? (bb.x - bb.y) : 0.f;
    float Cr2 = inM ? (bb.z + bb.z) : 0.f;
    float Ci2 = inM ? (bb.w + bb.w) : 0.f;
    K1[w-1].x = Cp;        K1[w-1].y = Cm;
    K2[w-1].x = Cm + Cm;   K2[w-1].y = Cp + Cp;
    K3[w-1].x = Cr2;       K3[w-1].y = Ci2;
    K4[w-1].x = -(Ci2+Ci2); K4[w-1].y = Cr2 + Cr2;
  }

  // ---- pin chain constants into VGPRs (free at 1 wave/EU budget) ----
  #pragma unroll
  for (int w = 0; w < 9; w++) { pinv(K1[w]); pinv(K2[w]); pinv(K3[w]); pinv(K4[w]); }
  #pragma unroll
  for (int j = 0; j < NH; j++) pin(wh[j]);
  pinv(QnA); pinv(QnB); pinv(QnG); pinv(QeA); pinv(QeB); pinv(QeG);
  pinv(KA); pinv(KB); pinv(KC); pinv(KD);

  // wave-uniform activation constants: g==2 -> tanh(x) = 2*sigm(2x) - 1
  const float se = (g == 2) ? -2.f : -1.f;
  const float sa = (g == 2) ?  2.f :  1.f;
  const float sb = (g == 2) ? -1.f :  0.f;

  float cstate = 0.f, hval = 0.f;
  float wxcur = lwx[g][0][hrow];      // prefetched W.x for t=0

  for (int t = 0; t < TS; t++) {
    const int tb = t & 1;

    // ---- (a) pre-activation: prefetched wx + tree-reduced recurrent dot ----
    float h0 = rl(hval,0), h1 = rl(hval,1), h2 = rl(hval,2), h3 = rl(hval,3), h4 = rl(hval,4);
    float h5 = rl(hval,5), h6 = rl(hval,6), h7 = rl(hval,7), h8 = rl(hval,8), h9 = rl(hval,9);
    float p0 = fmaf(wh[1], h1, wh[0]*h0);
    float p1 = fmaf(wh[3], h3, wh[2]*h2);
    float p2 = fmaf(wh[5], h5, wh[4]*h4);
    float p3 = fmaf(wh[7], h7, wh[6]*h6);
    float p4 = fmaf(wh[9], h9, wh[8]*h8);
    float pre = wxcur + ((p0 + p1) + (p2 + p3) + p4);

    wxcur = lwx[g][(t+1) & (TS-1)][hrow];

    // full-angle sin/cos (|pre| small); packed qeval for {n0,n1},{e1r,e1i}
    float th = pre * 0.15915494309189535f;
    f32x2 CS; CS.x = __builtin_amdgcn_cosf(th); CS.y = __builtin_amdgcn_sinf(th);
    f32x2 NP = pk_fma_s1lo(QnB, CS, pk_fma_s1hi(QnG, CS, QnA));
    f32x2 EP = pk_fma_s1lo(QeB, CS, pk_fma_s1hi(QeG, CS, QeA));

    // ---- (c) packed chain: P1={Q,S}, P2={A,Bn}; v's via readlane pairs ----
    f32x2 V1 = rl2(NP, 0), V2 = rl2(EP, 0);
    f32x2 P1 = pk_fma_s1hi(KB, V1, pk_mul_s1lo(KA, V1));   // {Q,S}
    f32x2 P2 = pk_fma_s1swap(KD, V2, pk_mul(KC, V2));      // {A,Bn}
    #pragma unroll
    for (int w = 1; w <= 9; w++) {
      f32x2 W1 = rl2(NP, w), W2 = rl2(EP, w);
      f32x2 U  = pk_addsub_ll(P1, P2);          // {Q+A, Q-A}
      f32x2 M  = pk_mul(U, W1);                 // {m0, m3}
      f32x2 T1 = pk_mul_s0hi(P1, W2);           // {S*vr, S*vi}
      f32x2 AB = pk_fma_am(P2, W2, T1);         // {am, bm}
      f32x2 QS = pk_addsub_lh(M, M);            // {q2, s2}
      f32x2 T2 = pk_mul_s0lo(QS, K1[w-1]);      // {q2*Cp, q2*Cm}
      P1 = pk_fma_s0lo(AB, K2[w-1], T2);        // {Q', S'}
      f32x2 T3 = pk_mul_s0hi(QS, K3[w-1]);      // {s2*Cr2, s2*Ci2}
      P2 = pk_fma_s0hi(AB, K4[w-1], T3);        // {A', Bn'}
    }

    // ---- (d) pick (scales pre-folded) + quad-sum; activation PRE-barrier ----
    float Qv = P1.x, Sv = P1.y, Av = P2.x, Bv = P2.y;
    float QpS = Qv + Sv;
    float QmS = Qv - Sv;
    float t0 = (sg & 1) ? Av  : QpS;
    float t1 = (sg & 1) ? QmS : Bv;
    float Ee = (sg & 2) ? t1 : t0;
    Ee += dppx<0xB1>(Ee);
    Ee += dppx<0x4E>(Ee);
    if ((lane & 3) == 0 && hq < NH) {
      lq[tb][hq][g] = fmaf(sa, 1.f/(1.f + __expf(se*Ee)), sb);
    }
    __syncthreads();   // the one barrier (no vmem in flight: lgkm-only drain)

    // ---- (f) LSTM cell: single b128 broadcast read of (f,i,g,o) ----
    float4 gates = *reinterpret_cast<const float4*>(&lq[tb][hrow][0]);
    cstate = gates.x*cstate + gates.y*gates.z;
    hval = gates.w*tanhr(cstate);
    // buffer h-output in LDS (lgkm only) -- written to HBM after the loop
    if (g == 0 && lane < NH) lhout[t][lane] = hval;
  }

  // ---- bulk coalesced h-output write (off the serial path) ----
  __syncthreads();
  for (int i = tid; i < TS*NH; i += 256) {
    int tt = i / NH, h = i - tt*NH;
    out[(size_t)tt*(NB*NH) + b*NH + h] = lhout[tt][h];
  }
  if (g == 0 && lane < NH) {
    out[(size_t)TS*NB*NH + b*NH + lane]          = hval;
    out[(size_t)TS*NB*NH + NB*NH + b*NH + lane]  = cstate;
  }
}

extern "C" void kernel_launch(void* const* d_in, const int* in_sizes, int n_in,
                              void* d_out, int out_size, void* d_ws, size_t ws_size,
                              hipStream_t stream) {
  (void)in_sizes; (void)n_in; (void)d_ws; (void)ws_size; (void)out_size;
  qlstm_kernel<<<dim3(NB), dim3(256), 0, stream>>>(
      (const float*)d_in[0], (const float*)d_in[1],
      (const float*)d_in[2], (const float*)d_in[3],
      (const float*)d_in[4], (const float*)d_in[5],
      (const float*)d_in[6], (const float*)d_in[7],
      (const float*)d_in[8], (const float*)d_in[9],
      (float*)d_out);
}